// Round 9
// baseline (4380.790 us; speedup 1.0000x reference)
//
#include <hip/hip_runtime.h>
#include <hip/hip_bf16.h>

typedef __hip_bfloat16 bf16;
typedef unsigned short ushort_t;

#define NEG 0.2f
#define LNEPS 1e-5f

// slot plausibility as a bf16 value: zero or exponent in [100,140]
__device__ __forceinline__ int plaus(unsigned int lo){
    lo &= 0x7FFFu;
    if (lo == 0) return 1;
    unsigned int ex = (lo >> 7) & 0xFF;
    return (ex >= 100 && ex <= 140) ? 1 : 0;
}

// decode element i of a maybe-bf16(fl=0)/maybe-fp32(fl=1) buffer via ushort slots
__device__ __forceinline__ float decode_slot(const ushort_t* s, long long i, int fl){
    long long base = i << fl;
    unsigned int hi = s[base + fl];
    unsigned int lo = s[base];
    unsigned int bits = (hi << 16) | (lo * (unsigned int)fl);
    return __uint_as_float(bits);
}

// ---------- per-tensor dtype flags ----------
__global__ void k_detect(const void* t0, const void* t1, const void* t2, const void* t3,
                         const void* t4, const void* t5, const void* t6, const void* t7,
                         const void* t8, const void* lng, int* flags){
    int t = threadIdx.x;
    if (blockIdx.x != 0) return;
    if (t < 9){
        const void* ptrs[9] = {t0,t1,t2,t3,t4,t5,t6,t7,t8};
        const ushort_t* w = (const ushort_t*)ptrs[t];
        int all_bf = 1;
        for (int i = 0; i < 16; i++) all_bf &= plaus((unsigned int)w[i]);
        flags[t] = all_bf ? 0 : 1;
    } else if (t == 9){
        const ushort_t* w = (const ushort_t*)lng;
        flags[9] = (w[0] == 0x3F80u) ? 0 : 1;
    }
}

// ---------- stage all 15 float params into fp32 block P ----------
#define P_TOTAL 56577
__global__ void k_convert(const void* p0, const void* p1, const void* p2, const void* p3,
        const void* p4, const void* p5, const void* p6, const void* p7, const void* p8,
        const void* p9, const void* p10, const void* p11, const void* p12, const void* p13,
        const void* p14, const int* flags, float* P){
    int idx = blockIdx.x*blockDim.x + threadIdx.x;
    if (idx >= P_TOTAL) return;
    const int sizes[15] = {4096,64,12288,12288,192,192,192,24576,192,192,192,2048,32,32,1};
    const int fidx[15]  = {1,  -1,  2,    3,    4,  5,  -1, 6,    -1, 9,  -1, 7,   -1,8, -1};
    const void* ptrs[15] = {p0,p1,p2,p3,p4,p5,p6,p7,p8,p9,p10,p11,p12,p13,p14};
    int s = 0, base = 0;
    while (idx - base >= sizes[s]){ base += sizes[s]; s++; }
    int li = idx - base;
    int fi = fidx[s];
    int fl = (fi >= 0) ? flags[fi] : 0;
    P[idx] = decode_slot((const ushort_t*)ptrs[s], li, fl);
}

// ---------- CSR build ----------
__global__ void k_hist(const int* __restrict__ row, const int* __restrict__ col,
                       int* __restrict__ cnt_r, int* __restrict__ cnt_c, int E){
    int e = blockIdx.x*blockDim.x + threadIdx.x;
    if (e < E){ atomicAdd(&cnt_r[row[e]], 1); atomicAdd(&cnt_c[col[e]], 1); }
}

// two blocks: 0 -> row scan, 1 -> col scan (+dinv)
__global__ __launch_bounds__(1024) void k_scan(const int* __restrict__ cnt_r,
        const int* __restrict__ cnt_c, int* __restrict__ ptr_r, int* __restrict__ ptr_c,
        int* __restrict__ nxt_r, int* __restrict__ nxt_c, float* __restrict__ dinv, int N){
    __shared__ int part[1024];
    const int* cnt = blockIdx.x ? cnt_c : cnt_r;
    int* ptr = blockIdx.x ? ptr_c : ptr_r;
    int* nxt = blockIdx.x ? nxt_c : nxt_r;
    int t = threadIdx.x;
    int chunk = (N + 1023) >> 10;
    int s0 = t*chunk, s1 = s0+chunk; if (s1 > N) s1 = N; if (s0 > N) s0 = N;
    int sum = 0;
    for (int i = s0; i < s1; i++) sum += cnt[i];
    part[t] = sum; __syncthreads();
    for (int off = 1; off < 1024; off <<= 1){
        int add = (t >= off) ? part[t-off] : 0;
        __syncthreads();
        part[t] += add;
        __syncthreads();
    }
    int running = part[t] - sum;       // exclusive prefix
    for (int i = s0; i < s1; i++){
        ptr[i] = running; nxt[i] = running;
        if (blockIdx.x){
            int d = cnt[i];
            dinv[i] = d > 0 ? rsqrtf((float)d) : 0.f;
        }
        running += cnt[i];
    }
    if (t == 1023) ptr[N] = part[1023];
}

__global__ void k_scatter(const int* __restrict__ row, const int* __restrict__ col,
        const float* __restrict__ dinv, int* __restrict__ nxt_r, int* __restrict__ nxt_c,
        int* __restrict__ re_col, float* __restrict__ re_val, int* __restrict__ ce_row, int E){
    int e = blockIdx.x*blockDim.x + threadIdx.x;
    if (e >= E) return;
    int r = row[e], c = col[e];
    float val = dinv[r]*dinv[c];
    int p = atomicAdd(&nxt_r[r], 1);
    re_col[p] = c; re_val[p] = val;
    int q = atomicAdd(&nxt_c[c], 1);
    ce_row[q] = r;
}

// ---------- precompute fused weights ----------
__global__ void k_prew(const float* __restrict__ fus_W, const float* __restrict__ e8_W,
                       const float* __restrict__ gat_b, const float* __restrict__ fus_b,
                       float* __restrict__ W1c, float* __restrict__ b2c){
    int t = blockIdx.x*blockDim.x + threadIdx.x;
    if (t < 3*4096){
        int i = t >> 12, jq = t & 4095, j = jq >> 6, q = jq & 63;
        const float* fw = fus_W + (size_t)i*64*128 + (size_t)j*128;
        const float* ew = e8_W + (size_t)i*4096;
        float acc = 0.f;
        for (int p = 0; p < 64; p++) acc += fw[p] * ew[p*64+q];
        W1c[t] = acc;
    }
    if (t < 3*64){
        int i = t >> 6, j = t & 63;
        const float* fw = fus_W + (size_t)i*64*128 + (size_t)j*128 + 64;
        float acc = fus_b[i*64+j];
        for (int p = 0; p < 64; p++) acc += gat_b[i*64+p] * fw[p];
        b2c[t] = acc;
    }
}

// ---------- embedding ----------
__global__ __launch_bounds__(256) void k_embed(const ushort_t* __restrict__ xs,
        const int* __restrict__ flags, const float* __restrict__ W,
        const float* __restrict__ b, float* __restrict__ h, int N){
    __shared__ float Wt[64*64];
    for (int idx = threadIdx.x; idx < 4096; idx += 256){
        int k = idx >> 6, j = idx & 63;
        Wt[idx] = W[j*64+k];
    }
    __syncthreads();
    int fl = flags[0];
    int lane = threadIdx.x & 63;
    int wid  = (blockIdx.x*blockDim.x + threadIdx.x) >> 6;
    int nw   = (gridDim.x*blockDim.x) >> 6;
    float bj = b[lane];
    for (int v = wid; v < N; v += nw){
        float xj = decode_slot(xs, (long long)v*64 + lane, fl);
        float acc = bj;
        #pragma unroll
        for (int k = 0; k < 64; k++) acc += __shfl(xj, k) * Wt[k*64+lane];
        h[(size_t)v*64 + lane] = acc;
    }
}

// ---------- per-layer: g = h @ gat_W, head sums ----------
__global__ __launch_bounds__(256) void k_gat_g(const float* __restrict__ h,
        const float* __restrict__ gatW, const float* __restrict__ att_src,
        const float* __restrict__ att_dst, float* __restrict__ G,
        float* __restrict__ a_s, float* __restrict__ a_d, int N){
    __shared__ float Ws[64*64];
    for (int idx = threadIdx.x; idx < 4096; idx += 256) Ws[idx] = gatW[idx];
    __syncthreads();
    int lane = threadIdx.x & 63, hh = lane >> 4;
    float asrc = att_src[lane];
    float adst = att_dst[lane];
    int wid = (blockIdx.x*blockDim.x + threadIdx.x) >> 6;
    int nw  = (gridDim.x*blockDim.x) >> 6;
    for (int v = wid; v < N; v += nw){
        float hj = h[(size_t)v*64 + lane];
        float g = 0.f;
        #pragma unroll
        for (int k = 0; k < 64; k++) g += __shfl(hj, k) * Ws[k*64+lane];
        G[(size_t)v*64 + lane] = g;
        float ts = g*asrc, td = g*adst;
        #pragma unroll
        for (int o = 1; o < 16; o <<= 1){ ts += __shfl_xor(ts, o); td += __shfl_xor(td, o); }
        if ((lane & 15) == 0){
            a_s[v*4+hh] = ts; a_d[v*4+hh] = td;
        }
    }
}

// ---------- per-layer mega-fused: e8 gather + online-softmax GAT gather +
//            fusion matmuls + residual + LN + ReLU.  reads h_in, writes h_out ----------
__global__ __launch_bounds__(256) void k_layer(const float* __restrict__ h_in,
        float* __restrict__ h_out, const float* __restrict__ G,
        const float* __restrict__ a_s, const float* __restrict__ a_d,
        const int* __restrict__ row_ptr, const int* __restrict__ re_col,
        const float* __restrict__ re_val,
        const int* __restrict__ col_ptr, const int* __restrict__ ce_row,
        const float* __restrict__ W1c, const float* __restrict__ fus_W,
        const float* __restrict__ b2c, const float* __restrict__ ln_g,
        const float* __restrict__ ln_b, int N){
    __shared__ float WT1[64*64];                // WT1[q*64+j] = W1c[j][q]
    __shared__ float WT2[64*64];                // WT2[p*64+j] = fus_W[j][64+p]
    for (int idx = threadIdx.x; idx < 4096; idx += 256){
        int a0 = idx >> 6, j = idx & 63;
        WT1[idx] = W1c[j*64 + a0];
        WT2[idx] = fus_W[j*128 + 64 + a0];
    }
    __syncthreads();
    int lane = threadIdx.x & 63, hh = lane >> 4;
    float lng = ln_g[lane], lnb = ln_b[lane];
    float bj = b2c[lane];
    int wid = (blockIdx.x*blockDim.x + threadIdx.x) >> 6;
    int nw  = (gridDim.x*blockDim.x) >> 6;
    for (int v = wid; v < N; v += nw){
        // --- e8: Aj = sum_{e: row=v} val * h_in[col] ---
        float Aj = 0.f;
        int rs = row_ptr[v], re = row_ptr[v+1];
        for (int i = rs; i < re; i++){
            int c = re_col[i];
            float val = re_val[i];
            Aj += val * h_in[(size_t)c*64 + lane];
        }
        // --- GAT: online softmax over incoming edges + self-loop ---
        float adv = a_d[v*4+hh];
        float t0 = a_s[v*4+hh] + adv; t0 = t0 > 0.f ? t0 : NEG*t0;
        float mm = t0, ss = 1.f;
        float acc = G[(size_t)v*64 + lane];
        int cs = col_ptr[v], ce = col_ptr[v+1];
        for (int i = cs; i < ce; i++){
            int r = ce_row[i];
            float t = a_s[r*4+hh] + adv; t = t > 0.f ? t : NEG*t;
            float nm = fmaxf(mm, t);
            float sc = __expf(mm - nm);
            float ee = __expf(t - nm);
            acc = acc*sc + ee*G[(size_t)r*64 + lane];
            ss = ss*sc + ee;
            mm = nm;
        }
        float xg = acc / ss;
        // --- fusion matmuls + residual ---
        float y = bj + h_in[(size_t)v*64 + lane];
        #pragma unroll
        for (int q = 0; q < 64; q++) y += __shfl(Aj, q) * WT1[q*64+lane];
        #pragma unroll
        for (int p = 0; p < 64; p++) y += __shfl(xg, p) * WT2[p*64+lane];
        // --- LN + ReLU ---
        float mu = y;
        #pragma unroll
        for (int o = 1; o < 64; o <<= 1) mu += __shfl_xor(mu, o);
        mu *= (1.f/64.f);
        float d = y - mu, var = d*d;
        #pragma unroll
        for (int o = 1; o < 64; o <<= 1) var += __shfl_xor(var, o);
        var *= (1.f/64.f);
        float out = d * rsqrtf(var + LNEPS) * lng + lnb;
        h_out[(size_t)v*64+lane] = out > 0.f ? out : 0.f;
    }
}

// ---------- readout: fp32 output ----------
__global__ __launch_bounds__(256) void k_readout(const float* __restrict__ h,
        const float* __restrict__ W1, const float* __restrict__ b1,
        const float* __restrict__ W2, const float* __restrict__ b2,
        float* __restrict__ out, int N){
    __shared__ float W1t[64*32];
    for (int idx = threadIdx.x; idx < 2048; idx += 256){
        int k = idx >> 5, j = idx & 31;
        W1t[idx] = W1[j*64+k];
    }
    __syncthreads();
    int lane = threadIdx.x & 63;
    float w2  = (lane < 32) ? W2[lane] : 0.f;
    float b1v = (lane < 32) ? b1[lane] : 0.f;
    float b2v = b2[0];
    int wid = (blockIdx.x*blockDim.x + threadIdx.x) >> 6;
    int nw  = (gridDim.x*blockDim.x) >> 6;
    for (int v = wid; v < N; v += nw){
        float hj = h[(size_t)v*64+lane];
        float acc = b1v;
        #pragma unroll
        for (int k = 0; k < 64; k++){
            float hk = __shfl(hj, k);
            if (lane < 32) acc += hk * W1t[k*32+lane];
        }
        float h1 = acc > 0.f ? acc : 0.f;
        float p = h1 * w2;
        #pragma unroll
        for (int o = 1; o < 32; o <<= 1) p += __shfl_xor(p, o);
        if (lane == 0){
            float z = p + b2v;
            out[v] = 1.f/(1.f + __expf(-z));
        }
    }
}

extern "C" void kernel_launch(void* const* d_in, const int* in_sizes, int n_in,
                              void* d_out, int out_size, void* d_ws, size_t ws_size,
                              hipStream_t stream){
    const ushort_t* xs = (const ushort_t*)d_in[0];
    const int*      ei = (const int*)d_in[1];

    int N = in_sizes[0] / 64;
    int E = in_sizes[1] / 2;
    const int* row = ei;
    const int* col = ei + E;

    float* f = (float*)d_ws;
    size_t o = 0;
    int*   flags = (int*)(f + o); o += 16;
    float* P     = f + o; o += P_TOTAL + 63;
    float* h1    = f + o; o += (size_t)N*64;
    float* h2    = f + o; o += (size_t)N*64;
    float* G     = f + o; o += (size_t)N*64;
    float* a_s   = f + o; o += (size_t)N*4;
    float* a_d   = f + o; o += (size_t)N*4;
    float* dinv  = f + o; o += (size_t)N;
    int* cnt_r   = (int*)(f + o); o += (size_t)N;
    int* cnt_c   = (int*)(f + o); o += (size_t)N;
    int* ptr_r   = (int*)(f + o); o += (size_t)N + 1;
    int* ptr_c   = (int*)(f + o); o += (size_t)N + 1;
    int* nxt_r   = (int*)(f + o); o += (size_t)N;
    int* nxt_c   = (int*)(f + o); o += (size_t)N;
    int* re_col  = (int*)(f + o); o += (size_t)E;
    float* re_val= f + o; o += (size_t)E;
    int* ce_row  = (int*)(f + o); o += (size_t)E;
    float* W1c   = f + o; o += 3*4096;
    float* b2c   = f + o; o += 3*64;

    const float* emb_W   = P + 0;
    const float* emb_b   = P + 4096;
    const float* e8_W    = P + 4160;
    const float* gat_W   = P + 16448;
    const float* att_src = P + 28736;
    const float* att_dst = P + 28928;
    const float* gat_b   = P + 29120;
    const float* fus_W   = P + 29312;
    const float* fus_b   = P + 53888;
    const float* ln_g    = P + 54080;
    const float* ln_b    = P + 54272;
    const float* r_W1    = P + 54464;
    const float* r_b1    = P + 56512;
    const float* r_W2    = P + 56544;
    const float* r_b2    = P + 56576;

    k_detect<<<1, 64, 0, stream>>>(d_in[0], d_in[2], d_in[4], d_in[5], d_in[6], d_in[7],
                                   d_in[9], d_in[13], d_in[15], d_in[11], flags);
    k_convert<<<(P_TOTAL+255)/256, 256, 0, stream>>>(
        d_in[2],d_in[3],d_in[4],d_in[5],d_in[6],d_in[7],d_in[8],d_in[9],
        d_in[10],d_in[11],d_in[12],d_in[13],d_in[14],d_in[15],d_in[16], flags, P);

    // CSR build
    hipMemsetAsync(cnt_r, 0, (size_t)N*sizeof(int), stream);
    hipMemsetAsync(cnt_c, 0, (size_t)N*sizeof(int), stream);
    k_hist<<<(E+255)/256, 256, 0, stream>>>(row, col, cnt_r, cnt_c, E);
    k_scan<<<2, 1024, 0, stream>>>(cnt_r, cnt_c, ptr_r, ptr_c, nxt_r, nxt_c, dinv, N);
    k_scatter<<<(E+255)/256, 256, 0, stream>>>(row, col, dinv, nxt_r, nxt_c,
                                               re_col, re_val, ce_row, E);

    k_prew<<<48, 256, 0, stream>>>(fus_W, e8_W, gat_b, fus_b, W1c, b2c);
    k_embed<<<1024, 256, 0, stream>>>(xs, flags, emb_W, emb_b, h1, N);

    float* hc = h1; float* hn = h2;
    for (int i = 0; i < 3; i++){
        k_gat_g<<<1024, 256, 0, stream>>>(hc, gat_W + (size_t)i*4096,
                                          att_src + i*64, att_dst + i*64,
                                          G, a_s, a_d, N);
        k_layer<<<2048, 256, 0, stream>>>(hc, hn, G, a_s, a_d,
                                          ptr_r, re_col, re_val, ptr_c, ce_row,
                                          W1c + i*4096, fus_W + (size_t)i*64*128, b2c + i*64,
                                          ln_g + i*64, ln_b + i*64, N);
        float* tmp = hc; hc = hn; hn = tmp;
    }
    k_readout<<<1024, 256, 0, stream>>>(hc, r_W1, r_b1, r_W2, r_b2, (float*)d_out, N);
}

// Round 10
// 2632.123 us; speedup vs baseline: 1.6644x; 1.6644x over previous
//
#include <hip/hip_runtime.h>
#include <hip/hip_bf16.h>

typedef __hip_bfloat16 bf16;
typedef unsigned short ushort_t;

#define NEG 0.2f
#define LNEPS 1e-5f

__device__ __forceinline__ int plaus(unsigned int lo){
    lo &= 0x7FFFu;
    if (lo == 0) return 1;
    unsigned int ex = (lo >> 7) & 0xFF;
    return (ex >= 100 && ex <= 140) ? 1 : 0;
}

__device__ __forceinline__ float decode_slot(const ushort_t* s, long long i, int fl){
    long long base = i << fl;
    unsigned int hi = s[base + fl];
    unsigned int lo = s[base];
    unsigned int bits = (hi << 16) | (lo * (unsigned int)fl);
    return __uint_as_float(bits);
}

// ---------- per-tensor dtype flags ----------
__global__ void k_detect(const void* t0, const void* t1, const void* t2, const void* t3,
                         const void* t4, const void* t5, const void* t6, const void* t7,
                         const void* t8, const void* lng, int* flags){
    int t = threadIdx.x;
    if (blockIdx.x != 0) return;
    if (t < 9){
        const void* ptrs[9] = {t0,t1,t2,t3,t4,t5,t6,t7,t8};
        const ushort_t* w = (const ushort_t*)ptrs[t];
        int all_bf = 1;
        for (int i = 0; i < 16; i++) all_bf &= plaus((unsigned int)w[i]);
        flags[t] = all_bf ? 0 : 1;
    } else if (t == 9){
        const ushort_t* w = (const ushort_t*)lng;
        flags[9] = (w[0] == 0x3F80u) ? 0 : 1;
    }
}

// ---------- stage params ----------
#define P_TOTAL 56577
__global__ void k_convert(const void* p0, const void* p1, const void* p2, const void* p3,
        const void* p4, const void* p5, const void* p6, const void* p7, const void* p8,
        const void* p9, const void* p10, const void* p11, const void* p12, const void* p13,
        const void* p14, const int* flags, float* P){
    int idx = blockIdx.x*blockDim.x + threadIdx.x;
    if (idx >= P_TOTAL) return;
    const int sizes[15] = {4096,64,12288,12288,192,192,192,24576,192,192,192,2048,32,32,1};
    const int fidx[15]  = {1,  -1,  2,    3,    4,  5,  -1, 6,    -1, 9,  -1, 7,   -1,8, -1};
    const void* ptrs[15] = {p0,p1,p2,p3,p4,p5,p6,p7,p8,p9,p10,p11,p12,p13,p14};
    int s = 0, base = 0;
    while (idx - base >= sizes[s]){ base += sizes[s]; s++; }
    int li = idx - base;
    int fi = fidx[s];
    int fl = (fi >= 0) ? flags[fi] : 0;
    P[idx] = decode_slot((const ushort_t*)ptrs[s], li, fl);
}

// ---------- CSR build ----------
// cnt[0..N) = out-deg by row ; cnt[N..2N) = in-deg by col
__global__ void k_hist(const int* __restrict__ row, const int* __restrict__ col,
                       int* __restrict__ cnt, int N, int E){
    int e = blockIdx.x*blockDim.x + threadIdx.x;
    if (e < E){ atomicAdd(&cnt[row[e]], 1); atomicAdd(&cnt[N + col[e]], 1); }
}

// standard 3-phase scan over n2 = 2N elements
__global__ __launch_bounds__(1024) void k_scan1(const int* __restrict__ cnt,
        int* __restrict__ tmp, int* __restrict__ bsum, int n2){
    __shared__ int sh[1024];
    int gid = blockIdx.x*1024 + threadIdx.x;
    int v = (gid < n2) ? cnt[gid] : 0;
    sh[threadIdx.x] = v; __syncthreads();
    for (int off = 1; off < 1024; off <<= 1){
        int add = (threadIdx.x >= off) ? sh[threadIdx.x - off] : 0;
        __syncthreads();
        sh[threadIdx.x] += add;
        __syncthreads();
    }
    if (gid < n2) tmp[gid] = sh[threadIdx.x];          // inclusive
    if (threadIdx.x == 1023) bsum[blockIdx.x] = sh[1023];
}
__global__ __launch_bounds__(256) void k_scan2(int* __restrict__ bsum, int nb){
    __shared__ int sh[256];
    int t = threadIdx.x;
    int v = (t < nb) ? bsum[t] : 0;
    sh[t] = v; __syncthreads();
    for (int off = 1; off < 256; off <<= 1){
        int add = (t >= off) ? sh[t - off] : 0;
        __syncthreads();
        sh[t] += add;
        __syncthreads();
    }
    if (t < nb) bsum[t] = sh[t] - v;                   // exclusive
}
__global__ void k_scan3(const int* __restrict__ cnt, const int* __restrict__ tmp,
        const int* __restrict__ bsum, int* __restrict__ ptr_r, int* __restrict__ nxt_r,
        int* __restrict__ ptr_c, int* __restrict__ nxt_c, float* __restrict__ dinv,
        int N, int E){
    int gid = blockIdx.x*blockDim.x + threadIdx.x;
    int n2 = 2*N;
    if (gid < n2){
        int excl = tmp[gid] - cnt[gid] + bsum[gid >> 10];
        if (gid < N){ ptr_r[gid] = excl; nxt_r[gid] = excl; }
        else {
            int j = gid - N;
            int e2 = excl - E;
            ptr_c[j] = e2; nxt_c[j] = e2;
            int d = cnt[gid];
            dinv[j] = d > 0 ? rsqrtf((float)d) : 0.f;
        }
    }
    if (gid == 0){ ptr_r[N] = E; ptr_c[N] = E; }
}

__global__ void k_scatter(const int* __restrict__ row, const int* __restrict__ col,
        const float* __restrict__ dinv, int* __restrict__ nxt_r, int* __restrict__ nxt_c,
        int* __restrict__ re_col, float* __restrict__ re_val, int* __restrict__ ce_row, int E){
    int e = blockIdx.x*blockDim.x + threadIdx.x;
    if (e >= E) return;
    int r = row[e], c = col[e];
    float val = dinv[r]*dinv[c];
    int p = atomicAdd(&nxt_r[r], 1);
    re_col[p] = c; re_val[p] = val;
    int q = atomicAdd(&nxt_c[c], 1);
    ce_row[q] = r;
}

// ---------- precompute fused weights ----------
__global__ void k_prew(const float* __restrict__ fus_W, const float* __restrict__ e8_W,
                       const float* __restrict__ gat_b, const float* __restrict__ fus_b,
                       float* __restrict__ W1c, float* __restrict__ b2c){
    int t = blockIdx.x*blockDim.x + threadIdx.x;
    if (t < 3*4096){
        int i = t >> 12, jq = t & 4095, j = jq >> 6, q = jq & 63;
        const float* fw = fus_W + (size_t)i*64*128 + (size_t)j*128;
        const float* ew = e8_W + (size_t)i*4096;
        float acc = 0.f;
        for (int p = 0; p < 64; p++) acc += fw[p] * ew[p*64+q];
        W1c[t] = acc;
    }
    if (t < 3*64){
        int i = t >> 6, j = t & 63;
        const float* fw = fus_W + (size_t)i*64*128 + (size_t)j*128 + 64;
        float acc = fus_b[i*64+j];
        for (int p = 0; p < 64; p++) acc += gat_b[i*64+p] * fw[p];
        b2c[t] = acc;
    }
}

// ---------- embedding ----------
__global__ __launch_bounds__(256) void k_embed(const ushort_t* __restrict__ xs,
        const int* __restrict__ flags, const float* __restrict__ W,
        const float* __restrict__ b, float* __restrict__ h, int N){
    __shared__ float Wt[64*64];
    for (int idx = threadIdx.x; idx < 4096; idx += 256){
        int k = idx >> 6, j = idx & 63;
        Wt[idx] = W[j*64+k];
    }
    __syncthreads();
    int fl = flags[0];
    int lane = threadIdx.x & 63;
    int wid  = (blockIdx.x*blockDim.x + threadIdx.x) >> 6;
    int nw   = (gridDim.x*blockDim.x) >> 6;
    float bj = b[lane];
    for (int v = wid; v < N; v += nw){
        float xj = decode_slot(xs, (long long)v*64 + lane, fl);
        float acc = bj;
        #pragma unroll
        for (int k = 0; k < 64; k++) acc += __shfl(xj, k) * Wt[k*64+lane];
        h[(size_t)v*64 + lane] = acc;
    }
}

// ---------- per-layer: g = h @ gat_W, head sums ----------
__global__ __launch_bounds__(256) void k_gat_g(const float* __restrict__ h,
        const float* __restrict__ gatW, const float* __restrict__ att_src,
        const float* __restrict__ att_dst, float* __restrict__ G,
        float* __restrict__ a_s, float* __restrict__ a_d, int N){
    __shared__ float Ws[64*64];
    for (int idx = threadIdx.x; idx < 4096; idx += 256) Ws[idx] = gatW[idx];
    __syncthreads();
    int lane = threadIdx.x & 63, hh = lane >> 4;
    float asrc = att_src[lane];
    float adst = att_dst[lane];
    int wid = (blockIdx.x*blockDim.x + threadIdx.x) >> 6;
    int nw  = (gridDim.x*blockDim.x) >> 6;
    for (int v = wid; v < N; v += nw){
        float hj = h[(size_t)v*64 + lane];
        float g = 0.f;
        #pragma unroll
        for (int k = 0; k < 64; k++) g += __shfl(hj, k) * Ws[k*64+lane];
        G[(size_t)v*64 + lane] = g;
        float ts = g*asrc, td = g*adst;
        #pragma unroll
        for (int o = 1; o < 16; o <<= 1){ ts += __shfl_xor(ts, o); td += __shfl_xor(td, o); }
        if ((lane & 15) == 0){
            a_s[v*4+hh] = ts; a_d[v*4+hh] = td;
        }
    }
}

__device__ __forceinline__ float leaky(float t){ return t > 0.f ? t : NEG*t; }

// ---------- per-layer mega-fused (two-phase softmax, 4x unrolled gathers) ----------
__global__ __launch_bounds__(256) void k_layer(const float* __restrict__ h_in,
        float* __restrict__ h_out, const float* __restrict__ G,
        const float* __restrict__ a_s, const float* __restrict__ a_d,
        const int* __restrict__ row_ptr, const int* __restrict__ re_col,
        const float* __restrict__ re_val,
        const int* __restrict__ col_ptr, const int* __restrict__ ce_row,
        const float* __restrict__ W1c, const float* __restrict__ fus_W,
        const float* __restrict__ b2c, const float* __restrict__ ln_g,
        const float* __restrict__ ln_b, int N){
    __shared__ float WT1[64*64];
    __shared__ float WT2[64*64];
    for (int idx = threadIdx.x; idx < 4096; idx += 256){
        int a0 = idx >> 6, j = idx & 63;
        WT1[idx] = W1c[j*64 + a0];
        WT2[idx] = fus_W[j*128 + 64 + a0];
    }
    __syncthreads();
    int lane = threadIdx.x & 63, hh = lane >> 4, sub = lane & 15;
    float lng = ln_g[lane], lnb = ln_b[lane];
    float bj = b2c[lane];
    int wid = (blockIdx.x*blockDim.x + threadIdx.x) >> 6;
    int nw  = (gridDim.x*blockDim.x) >> 6;
    for (int v = wid; v < N; v += nw){
        int cs = col_ptr[v], ce = col_ptr[v+1];
        float adv = a_d[v*4+hh];
        float t0 = leaky(a_s[v*4+hh] + adv);
        // --- phase 0: parallel max (16 lanes per head group scan the edge list) ---
        float mx = t0;
        for (int i = cs + sub; i < ce; i += 16){
            int r = ce_row[i];
            mx = fmaxf(mx, leaky(a_s[r*4+hh] + adv));
        }
        #pragma unroll
        for (int o = 1; o < 16; o <<= 1) mx = fmaxf(mx, __shfl_xor(mx, o));
        // --- e8 gather: 4 independent accumulators ---
        int rs = row_ptr[v], re = row_ptr[v+1];
        float Aj0 = 0.f, Aj1 = 0.f, Aj2 = 0.f, Aj3 = 0.f;
        int i = rs;
        for (; i + 3 < re; i += 4){
            int c0 = re_col[i], c1 = re_col[i+1], c2 = re_col[i+2], c3 = re_col[i+3];
            float v0 = re_val[i], v1 = re_val[i+1], v2 = re_val[i+2], v3 = re_val[i+3];
            Aj0 += v0 * h_in[(size_t)c0*64 + lane];
            Aj1 += v1 * h_in[(size_t)c1*64 + lane];
            Aj2 += v2 * h_in[(size_t)c2*64 + lane];
            Aj3 += v3 * h_in[(size_t)c3*64 + lane];
        }
        for (; i < re; i++)
            Aj0 += re_val[i] * h_in[(size_t)re_col[i]*64 + lane];
        float Aj = (Aj0 + Aj1) + (Aj2 + Aj3);
        // --- GAT gather: exp(t - mx), 4 independent accumulators ---
        float eesl = __expf(t0 - mx);
        float acc0 = eesl * G[(size_t)v*64 + lane], acc1 = 0.f, acc2 = 0.f, acc3 = 0.f;
        float ss0 = eesl, ss1 = 0.f, ss2 = 0.f, ss3 = 0.f;
        i = cs;
        for (; i + 3 < ce; i += 4){
            int r0 = ce_row[i], r1 = ce_row[i+1], r2 = ce_row[i+2], r3 = ce_row[i+3];
            float e0 = __expf(leaky(a_s[r0*4+hh] + adv) - mx);
            float e1 = __expf(leaky(a_s[r1*4+hh] + adv) - mx);
            float e2 = __expf(leaky(a_s[r2*4+hh] + adv) - mx);
            float e3 = __expf(leaky(a_s[r3*4+hh] + adv) - mx);
            acc0 += e0 * G[(size_t)r0*64 + lane]; ss0 += e0;
            acc1 += e1 * G[(size_t)r1*64 + lane]; ss1 += e1;
            acc2 += e2 * G[(size_t)r2*64 + lane]; ss2 += e2;
            acc3 += e3 * G[(size_t)r3*64 + lane]; ss3 += e3;
        }
        for (; i < ce; i++){
            int r = ce_row[i];
            float e0 = __expf(leaky(a_s[r*4+hh] + adv) - mx);
            acc0 += e0 * G[(size_t)r*64 + lane]; ss0 += e0;
        }
        float ssum = (ss0 + ss1) + (ss2 + ss3);
        float xg = ((acc0 + acc1) + (acc2 + acc3)) / ssum;
        // --- fusion matmuls + residual ---
        float y = bj + h_in[(size_t)v*64 + lane];
        #pragma unroll
        for (int q = 0; q < 64; q++) y += __shfl(Aj, q) * WT1[q*64+lane];
        #pragma unroll
        for (int p = 0; p < 64; p++) y += __shfl(xg, p) * WT2[p*64+lane];
        // --- LN + ReLU ---
        float mu = y;
        #pragma unroll
        for (int o = 1; o < 64; o <<= 1) mu += __shfl_xor(mu, o);
        mu *= (1.f/64.f);
        float d = y - mu, var = d*d;
        #pragma unroll
        for (int o = 1; o < 64; o <<= 1) var += __shfl_xor(var, o);
        var *= (1.f/64.f);
        float out = d * rsqrtf(var + LNEPS) * lng + lnb;
        h_out[(size_t)v*64+lane] = out > 0.f ? out : 0.f;
    }
}

// ---------- readout ----------
__global__ __launch_bounds__(256) void k_readout(const float* __restrict__ h,
        const float* __restrict__ W1, const float* __restrict__ b1,
        const float* __restrict__ W2, const float* __restrict__ b2,
        float* __restrict__ out, int N){
    __shared__ float W1t[64*32];
    for (int idx = threadIdx.x; idx < 2048; idx += 256){
        int k = idx >> 5, j = idx & 31;
        W1t[idx] = W1[j*64+k];
    }
    __syncthreads();
    int lane = threadIdx.x & 63;
    float w2  = (lane < 32) ? W2[lane] : 0.f;
    float b1v = (lane < 32) ? b1[lane] : 0.f;
    float b2v = b2[0];
    int wid = (blockIdx.x*blockDim.x + threadIdx.x) >> 6;
    int nw  = (gridDim.x*blockDim.x) >> 6;
    for (int v = wid; v < N; v += nw){
        float hj = h[(size_t)v*64+lane];
        float acc = b1v;
        #pragma unroll
        for (int k = 0; k < 64; k++){
            float hk = __shfl(hj, k);
            if (lane < 32) acc += hk * W1t[k*32+lane];
        }
        float h1 = acc > 0.f ? acc : 0.f;
        float p = h1 * w2;
        #pragma unroll
        for (int o = 1; o < 32; o <<= 1) p += __shfl_xor(p, o);
        if (lane == 0){
            float z = p + b2v;
            out[v] = 1.f/(1.f + __expf(-z));
        }
    }
}

extern "C" void kernel_launch(void* const* d_in, const int* in_sizes, int n_in,
                              void* d_out, int out_size, void* d_ws, size_t ws_size,
                              hipStream_t stream){
    const ushort_t* xs = (const ushort_t*)d_in[0];
    const int*      ei = (const int*)d_in[1];

    int N = in_sizes[0] / 64;
    int E = in_sizes[1] / 2;
    const int* row = ei;
    const int* col = ei + E;

    float* f = (float*)d_ws;
    size_t o = 0;
    int*   flags = (int*)(f + o); o += 16;
    float* P     = f + o; o += P_TOTAL + 63;
    float* h1    = f + o; o += (size_t)N*64;
    float* h2    = f + o; o += (size_t)N*64;
    float* G     = f + o; o += (size_t)N*64;
    float* a_s   = f + o; o += (size_t)N*4;
    float* a_d   = f + o; o += (size_t)N*4;
    float* dinv  = f + o; o += (size_t)N;
    int* cnt     = (int*)(f + o); o += (size_t)2*N;
    int* tmp     = (int*)(f + o); o += (size_t)2*N;
    int* bsum    = (int*)(f + o); o += 256;
    int* ptr_r   = (int*)(f + o); o += (size_t)N + 1;
    int* ptr_c   = (int*)(f + o); o += (size_t)N + 1;
    int* nxt_r   = (int*)(f + o); o += (size_t)N;
    int* nxt_c   = (int*)(f + o); o += (size_t)N;
    int* re_col  = (int*)(f + o); o += (size_t)E;
    float* re_val= f + o; o += (size_t)E;
    int* ce_row  = (int*)(f + o); o += (size_t)E;
    float* W1c   = f + o; o += 3*4096;
    float* b2c   = f + o; o += 3*64;

    const float* emb_W   = P + 0;
    const float* emb_b   = P + 4096;
    const float* e8_W    = P + 4160;
    const float* gat_W   = P + 16448;
    const float* att_src = P + 28736;
    const float* att_dst = P + 28928;
    const float* gat_b   = P + 29120;
    const float* fus_W   = P + 29312;
    const float* fus_b   = P + 53888;
    const float* ln_g    = P + 54080;
    const float* ln_b    = P + 54272;
    const float* r_W1    = P + 54464;
    const float* r_b1    = P + 56512;
    const float* r_W2    = P + 56544;
    const float* r_b2    = P + 56576;

    k_detect<<<1, 64, 0, stream>>>(d_in[0], d_in[2], d_in[4], d_in[5], d_in[6], d_in[7],
                                   d_in[9], d_in[13], d_in[15], d_in[11], flags);
    k_convert<<<(P_TOTAL+255)/256, 256, 0, stream>>>(
        d_in[2],d_in[3],d_in[4],d_in[5],d_in[6],d_in[7],d_in[8],d_in[9],
        d_in[10],d_in[11],d_in[12],d_in[13],d_in[14],d_in[15],d_in[16], flags, P);

    // CSR build
    int n2 = 2*N;
    int nb = (n2 + 1023) / 1024;
    hipMemsetAsync(cnt, 0, (size_t)n2*sizeof(int), stream);
    k_hist<<<(E+255)/256, 256, 0, stream>>>(row, col, cnt, N, E);
    k_scan1<<<nb, 1024, 0, stream>>>(cnt, tmp, bsum, n2);
    k_scan2<<<1, 256, 0, stream>>>(bsum, nb);
    k_scan3<<<(n2+255)/256, 256, 0, stream>>>(cnt, tmp, bsum, ptr_r, nxt_r, ptr_c, nxt_c,
                                              dinv, N, E);
    k_scatter<<<(E+255)/256, 256, 0, stream>>>(row, col, dinv, nxt_r, nxt_c,
                                               re_col, re_val, ce_row, E);

    k_prew<<<48, 256, 0, stream>>>(fus_W, e8_W, gat_b, fus_b, W1c, b2c);
    k_embed<<<1024, 256, 0, stream>>>(xs, flags, emb_W, emb_b, h1, N);

    float* hc = h1; float* hn = h2;
    for (int i = 0; i < 3; i++){
        k_gat_g<<<1024, 256, 0, stream>>>(hc, gat_W + (size_t)i*4096,
                                          att_src + i*64, att_dst + i*64,
                                          G, a_s, a_d, N);
        k_layer<<<2048, 256, 0, stream>>>(hc, hn, G, a_s, a_d,
                                          ptr_r, re_col, re_val, ptr_c, ce_row,
                                          W1c + i*4096, fus_W + (size_t)i*64*128, b2c + i*64,
                                          ln_g + i*64, ln_b + i*64, N);
        float* tmpp = hc; hc = hn; hn = tmpp;
    }
    k_readout<<<1024, 256, 0, stream>>>(hc, r_W1, r_b1, r_W2, r_b2, (float*)d_out, N);
}

// Round 11
// 2553.365 us; speedup vs baseline: 1.7157x; 1.0308x over previous
//
#include <hip/hip_runtime.h>
#include <hip/hip_bf16.h>
#include <hip/hip_fp16.h>

typedef __hip_bfloat16 bf16;
typedef unsigned short ushort_t;

#define NEG 0.2f
#define LNEPS 1e-5f

__device__ __forceinline__ int plaus(unsigned int lo){
    lo &= 0x7FFFu;
    if (lo == 0) return 1;
    unsigned int ex = (lo >> 7) & 0xFF;
    return (ex >= 100 && ex <= 140) ? 1 : 0;
}

__device__ __forceinline__ float decode_slot(const ushort_t* s, long long i, int fl){
    long long base = i << fl;
    unsigned int hi = s[base + fl];
    unsigned int lo = s[base];
    unsigned int bits = (hi << 16) | (lo * (unsigned int)fl);
    return __uint_as_float(bits);
}

// ---------- per-tensor dtype flags ----------
__global__ void k_detect(const void* t0, const void* t1, const void* t2, const void* t3,
                         const void* t4, const void* t5, const void* t6, const void* t7,
                         const void* t8, const void* lng, int* flags){
    int t = threadIdx.x;
    if (blockIdx.x != 0) return;
    if (t < 9){
        const void* ptrs[9] = {t0,t1,t2,t3,t4,t5,t6,t7,t8};
        const ushort_t* w = (const ushort_t*)ptrs[t];
        int all_bf = 1;
        for (int i = 0; i < 16; i++) all_bf &= plaus((unsigned int)w[i]);
        flags[t] = all_bf ? 0 : 1;
    } else if (t == 9){
        const ushort_t* w = (const ushort_t*)lng;
        flags[9] = (w[0] == 0x3F80u) ? 0 : 1;
    }
}

// ---------- stage params ----------
#define P_TOTAL 56577
__global__ void k_convert(const void* p0, const void* p1, const void* p2, const void* p3,
        const void* p4, const void* p5, const void* p6, const void* p7, const void* p8,
        const void* p9, const void* p10, const void* p11, const void* p12, const void* p13,
        const void* p14, const int* flags, float* P){
    int idx = blockIdx.x*blockDim.x + threadIdx.x;
    if (idx >= P_TOTAL) return;
    const int sizes[15] = {4096,64,12288,12288,192,192,192,24576,192,192,192,2048,32,32,1};
    const int fidx[15]  = {1,  -1,  2,    3,    4,  5,  -1, 6,    -1, 9,  -1, 7,   -1,8, -1};
    const void* ptrs[15] = {p0,p1,p2,p3,p4,p5,p6,p7,p8,p9,p10,p11,p12,p13,p14};
    int s = 0, base = 0;
    while (idx - base >= sizes[s]){ base += sizes[s]; s++; }
    int li = idx - base;
    int fi = fidx[s];
    int fl = (fi >= 0) ? flags[fi] : 0;
    P[idx] = decode_slot((const ushort_t*)ptrs[s], li, fl);
}

// ---------- CSR build ----------
__global__ void k_hist(const int* __restrict__ row, const int* __restrict__ col,
                       int* __restrict__ cnt, int N, int E){
    int e = blockIdx.x*blockDim.x + threadIdx.x;
    if (e < E){ atomicAdd(&cnt[row[e]], 1); atomicAdd(&cnt[N + col[e]], 1); }
}

__global__ __launch_bounds__(1024) void k_scan1(const int* __restrict__ cnt,
        int* __restrict__ tmp, int* __restrict__ bsum, int n2){
    __shared__ int sh[1024];
    int gid = blockIdx.x*1024 + threadIdx.x;
    int v = (gid < n2) ? cnt[gid] : 0;
    sh[threadIdx.x] = v; __syncthreads();
    for (int off = 1; off < 1024; off <<= 1){
        int add = (threadIdx.x >= off) ? sh[threadIdx.x - off] : 0;
        __syncthreads();
        sh[threadIdx.x] += add;
        __syncthreads();
    }
    if (gid < n2) tmp[gid] = sh[threadIdx.x];
    if (threadIdx.x == 1023) bsum[blockIdx.x] = sh[1023];
}
__global__ __launch_bounds__(256) void k_scan2(int* __restrict__ bsum, int nb){
    __shared__ int sh[256];
    int t = threadIdx.x;
    int v = (t < nb) ? bsum[t] : 0;
    sh[t] = v; __syncthreads();
    for (int off = 1; off < 256; off <<= 1){
        int add = (t >= off) ? sh[t - off] : 0;
        __syncthreads();
        sh[t] += add;
        __syncthreads();
    }
    if (t < nb) bsum[t] = sh[t] - v;
}
__global__ void k_scan3(const int* __restrict__ cnt, const int* __restrict__ tmp,
        const int* __restrict__ bsum, int* __restrict__ ptr_r, int* __restrict__ nxt_r,
        int* __restrict__ ptr_c, int* __restrict__ nxt_c, float* __restrict__ dinv,
        int N, int E){
    int gid = blockIdx.x*blockDim.x + threadIdx.x;
    int n2 = 2*N;
    if (gid < n2){
        int excl = tmp[gid] - cnt[gid] + bsum[gid >> 10];
        if (gid < N){ ptr_r[gid] = excl; nxt_r[gid] = excl; }
        else {
            int j = gid - N;
            int e2 = excl - E;
            ptr_c[j] = e2; nxt_c[j] = e2;
            int d = cnt[gid];
            dinv[j] = d > 0 ? rsqrtf((float)d) : 0.f;
        }
    }
    if (gid == 0){ ptr_r[N] = E; ptr_c[N] = E; }
}

__global__ void k_scatter(const int* __restrict__ row, const int* __restrict__ col,
        const float* __restrict__ dinv, int* __restrict__ nxt_r, int* __restrict__ nxt_c,
        int* __restrict__ re_col, float* __restrict__ re_val, int* __restrict__ ce_row, int E){
    int e = blockIdx.x*blockDim.x + threadIdx.x;
    if (e >= E) return;
    int r = row[e], c = col[e];
    float val = dinv[r]*dinv[c];
    int p = atomicAdd(&nxt_r[r], 1);
    re_col[p] = c; re_val[p] = val;
    int q = atomicAdd(&nxt_c[c], 1);
    ce_row[q] = r;
}

// ---------- precompute fused weights ----------
__global__ void k_prew(const float* __restrict__ fus_W, const float* __restrict__ e8_W,
                       const float* __restrict__ gat_b, const float* __restrict__ fus_b,
                       float* __restrict__ W1c, float* __restrict__ b2c){
    int t = blockIdx.x*blockDim.x + threadIdx.x;
    if (t < 3*4096){
        int i = t >> 12, jq = t & 4095, j = jq >> 6, q = jq & 63;
        const float* fw = fus_W + (size_t)i*64*128 + (size_t)j*128;
        const float* ew = e8_W + (size_t)i*4096;
        float acc = 0.f;
        for (int p = 0; p < 64; p++) acc += fw[p] * ew[p*64+q];
        W1c[t] = acc;
    }
    if (t < 3*64){
        int i = t >> 6, j = t & 63;
        const float* fw = fus_W + (size_t)i*64*128 + (size_t)j*128 + 64;
        float acc = fus_b[i*64+j];
        for (int p = 0; p < 64; p++) acc += gat_b[i*64+p] * fw[p];
        b2c[t] = acc;
    }
}

// ---------- embedding: writes h fp32 + h16 mirror ----------
__global__ __launch_bounds__(256) void k_embed(const ushort_t* __restrict__ xs,
        const int* __restrict__ flags, const float* __restrict__ W,
        const float* __restrict__ b, float* __restrict__ h, __half* __restrict__ h16, int N){
    __shared__ float Wt[64*64];
    for (int idx = threadIdx.x; idx < 4096; idx += 256){
        int k = idx >> 6, j = idx & 63;
        Wt[idx] = W[j*64+k];
    }
    __syncthreads();
    int fl = flags[0];
    int lane = threadIdx.x & 63;
    int wid  = (blockIdx.x*blockDim.x + threadIdx.x) >> 6;
    int nw   = (gridDim.x*blockDim.x) >> 6;
    float bj = b[lane];
    for (int v = wid; v < N; v += nw){
        float xj = decode_slot(xs, (long long)v*64 + lane, fl);
        float acc = bj;
        #pragma unroll
        for (int k = 0; k < 64; k++) acc += __shfl(xj, k) * Wt[k*64+lane];
        h[(size_t)v*64 + lane] = acc;
        h16[(size_t)v*64 + lane] = __float2half(acc);
    }
}

// ---------- per-layer: G16 = h @ gat_W (fp16), head sums ----------
__global__ __launch_bounds__(256) void k_gat_g(const float* __restrict__ h,
        const float* __restrict__ gatW, const float* __restrict__ att_src,
        const float* __restrict__ att_dst, __half* __restrict__ G16,
        float* __restrict__ a_s, float* __restrict__ a_d, int N){
    __shared__ float Ws[64*64];
    for (int idx = threadIdx.x; idx < 4096; idx += 256) Ws[idx] = gatW[idx];
    __syncthreads();
    int lane = threadIdx.x & 63, hh = lane >> 4;
    float asrc = att_src[lane];
    float adst = att_dst[lane];
    int wid = (blockIdx.x*blockDim.x + threadIdx.x) >> 6;
    int nw  = (gridDim.x*blockDim.x) >> 6;
    for (int v = wid; v < N; v += nw){
        float hj = h[(size_t)v*64 + lane];
        float g = 0.f;
        #pragma unroll
        for (int k = 0; k < 64; k++) g += __shfl(hj, k) * Ws[k*64+lane];
        G16[(size_t)v*64 + lane] = __float2half(g);
        float ts = g*asrc, td = g*adst;
        #pragma unroll
        for (int o = 1; o < 16; o <<= 1){ ts += __shfl_xor(ts, o); td += __shfl_xor(td, o); }
        if ((lane & 15) == 0){
            a_s[v*4+hh] = ts; a_d[v*4+hh] = td;
        }
    }
}

// ---------- per-head global maxes of a_s and a_d (two-stage, no init needed) ----------
__global__ __launch_bounds__(256) void k_headmax1(const float* __restrict__ a_s,
        const float* __restrict__ a_d, float* __restrict__ bmax_s,
        float* __restrict__ bmax_d, int n4){
    __shared__ float shs[256], shd[256];
    int t = threadIdx.x;
    int S = gridDim.x * 256;                  // multiple of 4
    float ms = -1e30f, md = -1e30f;
    for (int i = blockIdx.x*256 + t; i < n4; i += S){
        ms = fmaxf(ms, a_s[i]); md = fmaxf(md, a_d[i]);
    }
    shs[t] = ms; shd[t] = md; __syncthreads();
    for (int off = 128; off >= 4; off >>= 1){
        if (t < off){ shs[t] = fmaxf(shs[t], shs[t+off]); shd[t] = fmaxf(shd[t], shd[t+off]); }
        __syncthreads();
    }
    if (t < 4){ bmax_s[blockIdx.x*4+t] = shs[t]; bmax_d[blockIdx.x*4+t] = shd[t]; }
}
__global__ void k_headmax2(const float* __restrict__ bmax_s, const float* __restrict__ bmax_d,
                           float* __restrict__ mxs, int nb){
    int t = threadIdx.x;
    if (blockIdx.x != 0 || t >= 8) return;
    const float* src = (t < 4) ? bmax_s : bmax_d;
    int hh = t & 3;
    float m = -1e30f;
    for (int i = 0; i < nb; i++) m = fmaxf(m, src[i*4+hh]);
    mxs[t] = m;
}

__device__ __forceinline__ float leaky(float t){ return t > 0.f ? t : NEG*t; }

// ---------- per-layer mega-fused (global-shift softmax, fp16 gathers) ----------
__global__ __launch_bounds__(256) void k_layer(const float* __restrict__ h_in,
        const __half* __restrict__ h16_in, float* __restrict__ h_out,
        __half* __restrict__ h16_out, const __half* __restrict__ G16,
        const float* __restrict__ a_s, const float* __restrict__ a_d,
        const float* __restrict__ mxs,
        const int* __restrict__ row_ptr, const int* __restrict__ re_col,
        const float* __restrict__ re_val,
        const int* __restrict__ col_ptr, const int* __restrict__ ce_row,
        const float* __restrict__ W1c, const float* __restrict__ fus_W,
        const float* __restrict__ b2c, const float* __restrict__ ln_g,
        const float* __restrict__ ln_b, int N){
    __shared__ float WT1[64*64];
    __shared__ float WT2[64*64];
    for (int idx = threadIdx.x; idx < 4096; idx += 256){
        int a0 = idx >> 6, j = idx & 63;
        WT1[idx] = W1c[j*64 + a0];
        WT2[idx] = fus_W[j*128 + 64 + a0];
    }
    __syncthreads();
    int lane = threadIdx.x & 63, hh = lane >> 4;
    float lng = ln_g[lane], lnb = ln_b[lane];
    float bj = b2c[lane];
    float sh = leaky(mxs[hh] + mxs[4+hh]);    // per-head shift >= all logits
    int wid = (blockIdx.x*blockDim.x + threadIdx.x) >> 6;
    int nw  = (gridDim.x*blockDim.x) >> 6;
    for (int v = wid; v < N; v += nw){
        // --- e8 gather (fp16 mirror), 4 independent accumulators ---
        int rs = row_ptr[v], re = row_ptr[v+1];
        float Aj0 = 0.f, Aj1 = 0.f, Aj2 = 0.f, Aj3 = 0.f;
        int i = rs;
        for (; i + 3 < re; i += 4){
            int c0 = re_col[i], c1 = re_col[i+1], c2 = re_col[i+2], c3 = re_col[i+3];
            float v0 = re_val[i], v1 = re_val[i+1], v2 = re_val[i+2], v3 = re_val[i+3];
            Aj0 += v0 * __half2float(h16_in[(size_t)c0*64 + lane]);
            Aj1 += v1 * __half2float(h16_in[(size_t)c1*64 + lane]);
            Aj2 += v2 * __half2float(h16_in[(size_t)c2*64 + lane]);
            Aj3 += v3 * __half2float(h16_in[(size_t)c3*64 + lane]);
        }
        for (; i < re; i++)
            Aj0 += re_val[i] * __half2float(h16_in[(size_t)re_col[i]*64 + lane]);
        float Aj = (Aj0 + Aj1) + (Aj2 + Aj3);
        // --- GAT gather with global shift, 4 independent accumulators ---
        float adv = a_d[v*4+hh];
        float eesl = __expf(leaky(a_s[v*4+hh] + adv) - sh);
        float acc0 = eesl * __half2float(G16[(size_t)v*64 + lane]);
        float acc1 = 0.f, acc2 = 0.f, acc3 = 0.f;
        float ss0 = eesl, ss1 = 0.f, ss2 = 0.f, ss3 = 0.f;
        int cs = col_ptr[v], ce = col_ptr[v+1];
        i = cs;
        for (; i + 3 < ce; i += 4){
            int r0 = ce_row[i], r1 = ce_row[i+1], r2 = ce_row[i+2], r3 = ce_row[i+3];
            float e0 = __expf(leaky(a_s[r0*4+hh] + adv) - sh);
            float e1 = __expf(leaky(a_s[r1*4+hh] + adv) - sh);
            float e2 = __expf(leaky(a_s[r2*4+hh] + adv) - sh);
            float e3 = __expf(leaky(a_s[r3*4+hh] + adv) - sh);
            acc0 += e0 * __half2float(G16[(size_t)r0*64 + lane]); ss0 += e0;
            acc1 += e1 * __half2float(G16[(size_t)r1*64 + lane]); ss1 += e1;
            acc2 += e2 * __half2float(G16[(size_t)r2*64 + lane]); ss2 += e2;
            acc3 += e3 * __half2float(G16[(size_t)r3*64 + lane]); ss3 += e3;
        }
        for (; i < ce; i++){
            int r = ce_row[i];
            float e0 = __expf(leaky(a_s[r*4+hh] + adv) - sh);
            acc0 += e0 * __half2float(G16[(size_t)r*64 + lane]); ss0 += e0;
        }
        float ssum = (ss0 + ss1) + (ss2 + ss3);
        float xg = ((acc0 + acc1) + (acc2 + acc3)) / ssum;
        // --- fusion matmuls + residual ---
        float y = bj + h_in[(size_t)v*64 + lane];
        #pragma unroll
        for (int q = 0; q < 64; q++) y += __shfl(Aj, q) * WT1[q*64+lane];
        #pragma unroll
        for (int p = 0; p < 64; p++) y += __shfl(xg, p) * WT2[p*64+lane];
        // --- LN + ReLU ---
        float mu = y;
        #pragma unroll
        for (int o = 1; o < 64; o <<= 1) mu += __shfl_xor(mu, o);
        mu *= (1.f/64.f);
        float d = y - mu, var = d*d;
        #pragma unroll
        for (int o = 1; o < 64; o <<= 1) var += __shfl_xor(var, o);
        var *= (1.f/64.f);
        float out = d * rsqrtf(var + LNEPS) * lng + lnb;
        out = out > 0.f ? out : 0.f;
        h_out[(size_t)v*64+lane] = out;
        h16_out[(size_t)v*64+lane] = __float2half(out);
    }
}

// ---------- readout ----------
__global__ __launch_bounds__(256) void k_readout(const float* __restrict__ h,
        const float* __restrict__ W1, const float* __restrict__ b1,
        const float* __restrict__ W2, const float* __restrict__ b2,
        float* __restrict__ out, int N){
    __shared__ float W1t[64*32];
    for (int idx = threadIdx.x; idx < 2048; idx += 256){
        int k = idx >> 5, j = idx & 31;
        W1t[idx] = W1[j*64+k];
    }
    __syncthreads();
    int lane = threadIdx.x & 63;
    float w2  = (lane < 32) ? W2[lane] : 0.f;
    float b1v = (lane < 32) ? b1[lane] : 0.f;
    float b2v = b2[0];
    int wid = (blockIdx.x*blockDim.x + threadIdx.x) >> 6;
    int nw  = (gridDim.x*blockDim.x) >> 6;
    for (int v = wid; v < N; v += nw){
        float hj = h[(size_t)v*64+lane];
        float acc = b1v;
        #pragma unroll
        for (int k = 0; k < 64; k++){
            float hk = __shfl(hj, k);
            if (lane < 32) acc += hk * W1t[k*32+lane];
        }
        float h1 = acc > 0.f ? acc : 0.f;
        float p = h1 * w2;
        #pragma unroll
        for (int o = 1; o < 32; o <<= 1) p += __shfl_xor(p, o);
        if (lane == 0){
            float z = p + b2v;
            out[v] = 1.f/(1.f + __expf(-z));
        }
    }
}

extern "C" void kernel_launch(void* const* d_in, const int* in_sizes, int n_in,
                              void* d_out, int out_size, void* d_ws, size_t ws_size,
                              hipStream_t stream){
    const ushort_t* xs = (const ushort_t*)d_in[0];
    const int*      ei = (const int*)d_in[1];

    int N = in_sizes[0] / 64;
    int E = in_sizes[1] / 2;
    const int* row = ei;
    const int* col = ei + E;

    float* f = (float*)d_ws;
    size_t o = 0;
    int*   flags = (int*)(f + o); o += 16;
    float* P     = f + o; o += P_TOTAL + 63;
    float* h1    = f + o; o += (size_t)N*64;
    float* h2    = f + o; o += (size_t)N*64;
    __half* h1_16 = (__half*)(f + o); o += (size_t)N*32;
    __half* h2_16 = (__half*)(f + o); o += (size_t)N*32;
    __half* G16   = (__half*)(f + o); o += (size_t)N*32;
    float* a_s   = f + o; o += (size_t)N*4;
    float* a_d   = f + o; o += (size_t)N*4;
    float* mxs   = f + o; o += 16;
    float* bmax_s= f + o; o += 1024;
    float* bmax_d= f + o; o += 1024;
    float* dinv  = f + o; o += (size_t)N;
    int* cnt     = (int*)(f + o); o += (size_t)2*N;
    int* tmp     = (int*)(f + o); o += (size_t)2*N;
    int* bsum    = (int*)(f + o); o += 256;
    int* ptr_r   = (int*)(f + o); o += (size_t)N + 1;
    int* ptr_c   = (int*)(f + o); o += (size_t)N + 1;
    int* nxt_r   = (int*)(f + o); o += (size_t)N;
    int* nxt_c   = (int*)(f + o); o += (size_t)N;
    int* re_col  = (int*)(f + o); o += (size_t)E;
    float* re_val= f + o; o += (size_t)E;
    int* ce_row  = (int*)(f + o); o += (size_t)E;
    float* W1c   = f + o; o += 3*4096;
    float* b2c   = f + o; o += 3*64;

    const float* emb_W   = P + 0;
    const float* emb_b   = P + 4096;
    const float* e8_W    = P + 4160;
    const float* gat_W   = P + 16448;
    const float* att_src = P + 28736;
    const float* att_dst = P + 28928;
    const float* gat_b   = P + 29120;
    const float* fus_W   = P + 29312;
    const float* fus_b   = P + 53888;
    const float* ln_g    = P + 54080;
    const float* ln_b    = P + 54272;
    const float* r_W1    = P + 54464;
    const float* r_b1    = P + 56512;
    const float* r_W2    = P + 56544;
    const float* r_b2    = P + 56576;

    k_detect<<<1, 64, 0, stream>>>(d_in[0], d_in[2], d_in[4], d_in[5], d_in[6], d_in[7],
                                   d_in[9], d_in[13], d_in[15], d_in[11], flags);
    k_convert<<<(P_TOTAL+255)/256, 256, 0, stream>>>(
        d_in[2],d_in[3],d_in[4],d_in[5],d_in[6],d_in[7],d_in[8],d_in[9],
        d_in[10],d_in[11],d_in[12],d_in[13],d_in[14],d_in[15],d_in[16], flags, P);

    // CSR build
    int n2 = 2*N;
    int nb = (n2 + 1023) / 1024;
    hipMemsetAsync(cnt, 0, (size_t)n2*sizeof(int), stream);
    k_hist<<<(E+255)/256, 256, 0, stream>>>(row, col, cnt, N, E);
    k_scan1<<<nb, 1024, 0, stream>>>(cnt, tmp, bsum, n2);
    k_scan2<<<1, 256, 0, stream>>>(bsum, nb);
    k_scan3<<<(n2+255)/256, 256, 0, stream>>>(cnt, tmp, bsum, ptr_r, nxt_r, ptr_c, nxt_c,
                                              dinv, N, E);
    k_scatter<<<(E+255)/256, 256, 0, stream>>>(row, col, dinv, nxt_r, nxt_c,
                                               re_col, re_val, ce_row, E);

    k_prew<<<48, 256, 0, stream>>>(fus_W, e8_W, gat_b, fus_b, W1c, b2c);
    k_embed<<<1024, 256, 0, stream>>>(xs, flags, emb_W, emb_b, h1, h1_16, N);

    float* hc = h1; float* hn = h2;
    __half* hc16 = h1_16; __half* hn16 = h2_16;
    for (int i = 0; i < 3; i++){
        k_gat_g<<<1024, 256, 0, stream>>>(hc, gat_W + (size_t)i*4096,
                                          att_src + i*64, att_dst + i*64,
                                          G16, a_s, a_d, N);
        k_headmax1<<<256, 256, 0, stream>>>(a_s, a_d, bmax_s, bmax_d, N*4);
        k_headmax2<<<1, 64, 0, stream>>>(bmax_s, bmax_d, mxs, 256);
        k_layer<<<2048, 256, 0, stream>>>(hc, hc16, hn, hn16, G16, a_s, a_d, mxs,
                                          ptr_r, re_col, re_val, ptr_c, ce_row,
                                          W1c + i*4096, fus_W + (size_t)i*64*128, b2c + i*64,
                                          ln_g + i*64, ln_b + i*64, N);
        float* tf = hc; hc = hn; hn = tf;
        __half* th = hc16; hc16 = hn16; hn16 = th;
    }
    k_readout<<<1024, 256, 0, stream>>>(hc, r_W1, r_b1, r_W2, r_b2, (float*)d_out, N);
}

// Round 12
// 2045.288 us; speedup vs baseline: 2.1419x; 1.2484x over previous
//
#include <hip/hip_runtime.h>
#include <hip/hip_bf16.h>
#include <hip/hip_fp16.h>

typedef __hip_bfloat16 bf16;
typedef unsigned short ushort_t;

#define NEG 0.2f
#define LNEPS 1e-5f

__device__ __forceinline__ int plaus(unsigned int lo){
    lo &= 0x7FFFu;
    if (lo == 0) return 1;
    unsigned int ex = (lo >> 7) & 0xFF;
    return (ex >= 100 && ex <= 140) ? 1 : 0;
}

__device__ __forceinline__ float decode_slot(const ushort_t* s, long long i, int fl){
    long long base = i << fl;
    unsigned int hi = s[base + fl];
    unsigned int lo = s[base];
    unsigned int bits = (hi << 16) | (lo * (unsigned int)fl);
    return __uint_as_float(bits);
}

// ---------- per-tensor dtype flags ----------
__global__ void k_detect(const void* t0, const void* t1, const void* t2, const void* t3,
                         const void* t4, const void* t5, const void* t6, const void* t7,
                         const void* t8, const void* lng, int* flags){
    int t = threadIdx.x;
    if (blockIdx.x != 0) return;
    if (t < 9){
        const void* ptrs[9] = {t0,t1,t2,t3,t4,t5,t6,t7,t8};
        const ushort_t* w = (const ushort_t*)ptrs[t];
        int all_bf = 1;
        for (int i = 0; i < 16; i++) all_bf &= plaus((unsigned int)w[i]);
        flags[t] = all_bf ? 0 : 1;
    } else if (t == 9){
        const ushort_t* w = (const ushort_t*)lng;
        flags[9] = (w[0] == 0x3F80u) ? 0 : 1;
    }
}

// ---------- stage params ----------
#define P_TOTAL 56577
__global__ void k_convert(const void* p0, const void* p1, const void* p2, const void* p3,
        const void* p4, const void* p5, const void* p6, const void* p7, const void* p8,
        const void* p9, const void* p10, const void* p11, const void* p12, const void* p13,
        const void* p14, const int* flags, float* P){
    int idx = blockIdx.x*blockDim.x + threadIdx.x;
    if (idx >= P_TOTAL) return;
    const int sizes[15] = {4096,64,12288,12288,192,192,192,24576,192,192,192,2048,32,32,1};
    const int fidx[15]  = {1,  -1,  2,    3,    4,  5,  -1, 6,    -1, 9,  -1, 7,   -1,8, -1};
    const void* ptrs[15] = {p0,p1,p2,p3,p4,p5,p6,p7,p8,p9,p10,p11,p12,p13,p14};
    int s = 0, base = 0;
    while (idx - base >= sizes[s]){ base += sizes[s]; s++; }
    int li = idx - base;
    int fi = fidx[s];
    int fl = (fi >= 0) ? flags[fi] : 0;
    P[idx] = decode_slot((const ushort_t*)ptrs[s], li, fl);
}

// ---------- CSR build ----------
__global__ void k_hist(const int* __restrict__ row, const int* __restrict__ col,
                       int* __restrict__ cnt, int N, int E){
    int e = blockIdx.x*blockDim.x + threadIdx.x;
    if (e < E){ atomicAdd(&cnt[row[e]], 1); atomicAdd(&cnt[N + col[e]], 1); }
}

__global__ __launch_bounds__(1024) void k_scan1(const int* __restrict__ cnt,
        int* __restrict__ tmp, int* __restrict__ bsum, int n2){
    __shared__ int sh[1024];
    int gid = blockIdx.x*1024 + threadIdx.x;
    int v = (gid < n2) ? cnt[gid] : 0;
    sh[threadIdx.x] = v; __syncthreads();
    for (int off = 1; off < 1024; off <<= 1){
        int add = (threadIdx.x >= off) ? sh[threadIdx.x - off] : 0;
        __syncthreads();
        sh[threadIdx.x] += add;
        __syncthreads();
    }
    if (gid < n2) tmp[gid] = sh[threadIdx.x];
    if (threadIdx.x == 1023) bsum[blockIdx.x] = sh[1023];
}
__global__ __launch_bounds__(256) void k_scan2(int* __restrict__ bsum, int nb){
    __shared__ int sh[256];
    int t = threadIdx.x;
    int v = (t < nb) ? bsum[t] : 0;
    sh[t] = v; __syncthreads();
    for (int off = 1; off < 256; off <<= 1){
        int add = (t >= off) ? sh[t - off] : 0;
        __syncthreads();
        sh[t] += add;
        __syncthreads();
    }
    if (t < nb) bsum[t] = sh[t] - v;
}
__global__ void k_scan3(const int* __restrict__ cnt, const int* __restrict__ tmp,
        const int* __restrict__ bsum, int* __restrict__ ptr_r, int* __restrict__ nxt_r,
        int* __restrict__ ptr_c, int* __restrict__ nxt_c, float* __restrict__ dinv,
        int N, int E){
    int gid = blockIdx.x*blockDim.x + threadIdx.x;
    int n2 = 2*N;
    if (gid < n2){
        int excl = tmp[gid] - cnt[gid] + bsum[gid >> 10];
        if (gid < N){ ptr_r[gid] = excl; nxt_r[gid] = excl; }
        else {
            int j = gid - N;
            int e2 = excl - E;
            ptr_c[j] = e2; nxt_c[j] = e2;
            int d = cnt[gid];
            dinv[j] = d > 0 ? rsqrtf((float)d) : 0.f;
        }
    }
    if (gid == 0){ ptr_r[N] = E; ptr_c[N] = E; }
}

__global__ void k_scatter(const int* __restrict__ row, const int* __restrict__ col,
        int* __restrict__ nxt_r, int* __restrict__ nxt_c,
        int* __restrict__ re_col, int* __restrict__ ce_row, int E){
    int e = blockIdx.x*blockDim.x + threadIdx.x;
    if (e >= E) return;
    int r = row[e], c = col[e];
    int p = atomicAdd(&nxt_r[r], 1);
    re_col[p] = c;
    int q = atomicAdd(&nxt_c[c], 1);
    ce_row[q] = r;
}

// ---------- precompute fused weights ----------
__global__ void k_prew(const float* __restrict__ fus_W, const float* __restrict__ e8_W,
                       const float* __restrict__ gat_b, const float* __restrict__ fus_b,
                       float* __restrict__ W1c, float* __restrict__ b2c){
    int t = blockIdx.x*blockDim.x + threadIdx.x;
    if (t < 3*4096){
        int i = t >> 12, jq = t & 4095, j = jq >> 6, q = jq & 63;
        const float* fw = fus_W + (size_t)i*64*128 + (size_t)j*128;
        const float* ew = e8_W + (size_t)i*4096;
        float acc = 0.f;
        for (int p = 0; p < 64; p++) acc += fw[p] * ew[p*64+q];
        W1c[t] = acc;
    }
    if (t < 3*64){
        int i = t >> 6, j = t & 63;
        const float* fw = fus_W + (size_t)i*64*128 + (size_t)j*128 + 64;
        float acc = fus_b[i*64+j];
        for (int p = 0; p < 64; p++) acc += gat_b[i*64+p] * fw[p];
        b2c[t] = acc;
    }
}

// ---------- embedding: writes h fp32 + ht16 = dinv*h mirror ----------
__global__ __launch_bounds__(256) void k_embed(const ushort_t* __restrict__ xs,
        const int* __restrict__ flags, const float* __restrict__ W,
        const float* __restrict__ b, const float* __restrict__ dinv,
        float* __restrict__ h, __half* __restrict__ ht16, int N){
    __shared__ float Wt[64*64];
    for (int idx = threadIdx.x; idx < 4096; idx += 256){
        int k = idx >> 6, j = idx & 63;
        Wt[idx] = W[j*64+k];
    }
    __syncthreads();
    int fl = flags[0];
    int lane = threadIdx.x & 63;
    int wid  = (blockIdx.x*blockDim.x + threadIdx.x) >> 6;
    int nw   = (gridDim.x*blockDim.x) >> 6;
    float bj = b[lane];
    for (int v = wid; v < N; v += nw){
        float xj = decode_slot(xs, (long long)v*64 + lane, fl);
        float acc = bj;
        #pragma unroll
        for (int k = 0; k < 64; k++) acc += __shfl(xj, k) * Wt[k*64+lane];
        h[(size_t)v*64 + lane] = acc;
        ht16[(size_t)v*64 + lane] = __float2half(dinv[v]*acc);
    }
}

// ---------- per-layer: G16 = h @ gat_W (fp16), head sums ----------
__global__ __launch_bounds__(256) void k_gat_g(const float* __restrict__ h,
        const float* __restrict__ gatW, const float* __restrict__ att_src,
        const float* __restrict__ att_dst, __half* __restrict__ G16,
        float* __restrict__ a_s, float* __restrict__ a_d, int N){
    __shared__ float Ws[64*64];
    for (int idx = threadIdx.x; idx < 4096; idx += 256) Ws[idx] = gatW[idx];
    __syncthreads();
    int lane = threadIdx.x & 63, hh = lane >> 4;
    float asrc = att_src[lane];
    float adst = att_dst[lane];
    int wid = (blockIdx.x*blockDim.x + threadIdx.x) >> 6;
    int nw  = (gridDim.x*blockDim.x) >> 6;
    for (int v = wid; v < N; v += nw){
        float hj = h[(size_t)v*64 + lane];
        float g = 0.f;
        #pragma unroll
        for (int k = 0; k < 64; k++) g += __shfl(hj, k) * Ws[k*64+lane];
        G16[(size_t)v*64 + lane] = __float2half(g);
        float ts = g*asrc, td = g*adst;
        #pragma unroll
        for (int o = 1; o < 16; o <<= 1){ ts += __shfl_xor(ts, o); td += __shfl_xor(td, o); }
        if ((lane & 15) == 0){
            a_s[v*4+hh] = ts; a_d[v*4+hh] = td;
        }
    }
}

// ---------- per-head global maxes ----------
__global__ __launch_bounds__(256) void k_headmax1(const float* __restrict__ a_s,
        const float* __restrict__ a_d, float* __restrict__ bmax_s,
        float* __restrict__ bmax_d, int n4){
    __shared__ float shs[256], shd[256];
    int t = threadIdx.x;
    int S = gridDim.x * 256;
    float ms = -1e30f, md = -1e30f;
    for (int i = blockIdx.x*256 + t; i < n4; i += S){
        ms = fmaxf(ms, a_s[i]); md = fmaxf(md, a_d[i]);
    }
    shs[t] = ms; shd[t] = md; __syncthreads();
    for (int off = 128; off >= 4; off >>= 1){
        if (t < off){ shs[t] = fmaxf(shs[t], shs[t+off]); shd[t] = fmaxf(shd[t], shd[t+off]); }
        __syncthreads();
    }
    if (t < 4){ bmax_s[blockIdx.x*4+t] = shs[t]; bmax_d[blockIdx.x*4+t] = shd[t]; }
}
__global__ void k_headmax2(const float* __restrict__ bmax_s, const float* __restrict__ bmax_d,
                           float* __restrict__ mxs, int nb){
    int t = threadIdx.x;
    if (blockIdx.x != 0 || t >= 8) return;
    const float* src = (t < 4) ? bmax_s : bmax_d;
    int hh = t & 3;
    float m = -1e30f;
    for (int i = 0; i < nb; i++) m = fmaxf(m, src[i*4+hh]);
    mxs[t] = m;
}

__device__ __forceinline__ float leaky(float t){ return t > 0.f ? t : NEG*t; }

__device__ __forceinline__ float4 h4load(const ushort4* base, size_t rowe, int sub){
    ushort4 q = base[rowe*16 + sub];
    float4 r;
    r.x = __half2float(__ushort_as_half(q.x));
    r.y = __half2float(__ushort_as_half(q.y));
    r.z = __half2float(__ushort_as_half(q.z));
    r.w = __half2float(__ushort_as_half(q.w));
    return r;
}

// ---------- gather: 4 nodes/wave, 16 lanes/node, 4 ch/lane (8B loads) ----------
__global__ __launch_bounds__(256) void k_gather(const __half* __restrict__ ht16,
        const __half* __restrict__ G16,
        const float* __restrict__ a_s, const float* __restrict__ a_d,
        const float* __restrict__ mxs, const float* __restrict__ dinv,
        const int* __restrict__ row_ptr, const int* __restrict__ re_col,
        const int* __restrict__ col_ptr, const int* __restrict__ ce_row,
        __half* __restrict__ Aj16, __half* __restrict__ xg16, int N){
    int lane = threadIdx.x & 63;
    int grp  = lane >> 4;                 // node within wave
    int sub  = lane & 15;                 // 4-channel slot
    int hh   = sub >> 2;                  // head of this lane's channels
    int wid  = (blockIdx.x*blockDim.x + threadIdx.x) >> 6;
    int v    = wid*4 + grp;
    if (v >= N) return;
    const ushort4* htb = (const ushort4*)ht16;
    const ushort4* gb  = (const ushort4*)G16;
    float sh = leaky(mxs[hh] + mxs[4+hh]);
    // --- e8: Aj = dinv[v] * sum ht16[c] ---
    int rs = row_ptr[v], re = row_ptr[v+1];
    float4 a0 = {0,0,0,0}, a1 = {0,0,0,0}, a2 = {0,0,0,0}, a3 = {0,0,0,0};
    int i = rs;
    for (; i + 3 < re; i += 4){
        int c0 = re_col[i], c1 = re_col[i+1], c2 = re_col[i+2], c3 = re_col[i+3];
        float4 q0 = h4load(htb, c0, sub), q1 = h4load(htb, c1, sub);
        float4 q2 = h4load(htb, c2, sub), q3 = h4load(htb, c3, sub);
        a0.x += q0.x; a0.y += q0.y; a0.z += q0.z; a0.w += q0.w;
        a1.x += q1.x; a1.y += q1.y; a1.z += q1.z; a1.w += q1.w;
        a2.x += q2.x; a2.y += q2.y; a2.z += q2.z; a2.w += q2.w;
        a3.x += q3.x; a3.y += q3.y; a3.z += q3.z; a3.w += q3.w;
    }
    for (; i < re; i++){
        float4 q0 = h4load(htb, re_col[i], sub);
        a0.x += q0.x; a0.y += q0.y; a0.z += q0.z; a0.w += q0.w;
    }
    float dv = dinv[v];
    float4 Aj;
    Aj.x = dv*((a0.x+a1.x)+(a2.x+a3.x));
    Aj.y = dv*((a0.y+a1.y)+(a2.y+a3.y));
    Aj.z = dv*((a0.z+a1.z)+(a2.z+a3.z));
    Aj.w = dv*((a0.w+a1.w)+(a2.w+a3.w));
    // --- GAT: global-shift softmax gather ---
    float adv = a_d[v*4+hh];
    float eesl = __expf(leaky(a_s[v*4+hh] + adv) - sh);
    float4 g0 = h4load(gb, v, sub);
    float4 c0v = {eesl*g0.x, eesl*g0.y, eesl*g0.z, eesl*g0.w};
    float4 c1v = {0,0,0,0}, c2v = {0,0,0,0}, c3v = {0,0,0,0};
    float s0 = eesl, s1 = 0.f, s2 = 0.f, s3 = 0.f;
    int cs = col_ptr[v], ce = col_ptr[v+1];
    i = cs;
    for (; i + 3 < ce; i += 4){
        int r0 = ce_row[i], r1 = ce_row[i+1], r2 = ce_row[i+2], r3 = ce_row[i+3];
        float e0 = __expf(leaky(a_s[r0*4+hh] + adv) - sh);
        float e1 = __expf(leaky(a_s[r1*4+hh] + adv) - sh);
        float e2 = __expf(leaky(a_s[r2*4+hh] + adv) - sh);
        float e3 = __expf(leaky(a_s[r3*4+hh] + adv) - sh);
        float4 q0 = h4load(gb, r0, sub), q1 = h4load(gb, r1, sub);
        float4 q2 = h4load(gb, r2, sub), q3 = h4load(gb, r3, sub);
        c0v.x += e0*q0.x; c0v.y += e0*q0.y; c0v.z += e0*q0.z; c0v.w += e0*q0.w; s0 += e0;
        c1v.x += e1*q1.x; c1v.y += e1*q1.y; c1v.z += e1*q1.z; c1v.w += e1*q1.w; s1 += e1;
        c2v.x += e2*q2.x; c2v.y += e2*q2.y; c2v.z += e2*q2.z; c2v.w += e2*q2.w; s2 += e2;
        c3v.x += e3*q3.x; c3v.y += e3*q3.y; c3v.z += e3*q3.z; c3v.w += e3*q3.w; s3 += e3;
    }
    for (; i < ce; i++){
        int r0 = ce_row[i];
        float e0 = __expf(leaky(a_s[r0*4+hh] + adv) - sh);
        float4 q0 = h4load(gb, r0, sub);
        c0v.x += e0*q0.x; c0v.y += e0*q0.y; c0v.z += e0*q0.z; c0v.w += e0*q0.w; s0 += e0;
    }
    float ssum = (s0+s1)+(s2+s3);
    float inv = 1.f/ssum;
    float4 xg;
    xg.x = ((c0v.x+c1v.x)+(c2v.x+c3v.x))*inv;
    xg.y = ((c0v.y+c1v.y)+(c2v.y+c3v.y))*inv;
    xg.z = ((c0v.z+c1v.z)+(c2v.z+c3v.z))*inv;
    xg.w = ((c0v.w+c1v.w)+(c2v.w+c3v.w))*inv;
    // --- store fp16 ---
    ushort4 pa, px;
    pa.x = __half_as_ushort(__float2half(Aj.x));
    pa.y = __half_as_ushort(__float2half(Aj.y));
    pa.z = __half_as_ushort(__float2half(Aj.z));
    pa.w = __half_as_ushort(__float2half(Aj.w));
    px.x = __half_as_ushort(__float2half(xg.x));
    px.y = __half_as_ushort(__float2half(xg.y));
    px.z = __half_as_ushort(__float2half(xg.z));
    px.w = __half_as_ushort(__float2half(xg.w));
    ((ushort4*)Aj16)[(size_t)v*16 + sub] = pa;
    ((ushort4*)xg16)[(size_t)v*16 + sub] = px;
}

// ---------- fuse: matmuls + residual + LN + ReLU, in-place h ----------
__global__ __launch_bounds__(256) void k_fuse(float* __restrict__ h,
        const __half* __restrict__ Aj16, const __half* __restrict__ xg16,
        const float* __restrict__ dinv, __half* __restrict__ ht16,
        const float* __restrict__ W1c, const float* __restrict__ fus_W,
        const float* __restrict__ b2c, const float* __restrict__ ln_g,
        const float* __restrict__ ln_b, int N){
    __shared__ float WT1[64*64];
    __shared__ float WT2[64*64];
    for (int idx = threadIdx.x; idx < 4096; idx += 256){
        int a0 = idx >> 6, j = idx & 63;
        WT1[idx] = W1c[j*64 + a0];
        WT2[idx] = fus_W[j*128 + 64 + a0];
    }
    __syncthreads();
    int lane = threadIdx.x & 63;
    float lng = ln_g[lane], lnb = ln_b[lane];
    float bj = b2c[lane];
    int wid = (blockIdx.x*blockDim.x + threadIdx.x) >> 6;
    int nw  = (gridDim.x*blockDim.x) >> 6;
    for (int v = wid; v < N; v += nw){
        float Aj = __half2float(Aj16[(size_t)v*64 + lane]);
        float xg = __half2float(xg16[(size_t)v*64 + lane]);
        float y = bj + h[(size_t)v*64 + lane];
        #pragma unroll
        for (int q = 0; q < 64; q++) y += __shfl(Aj, q) * WT1[q*64+lane];
        #pragma unroll
        for (int p = 0; p < 64; p++) y += __shfl(xg, p) * WT2[p*64+lane];
        float mu = y;
        #pragma unroll
        for (int o = 1; o < 64; o <<= 1) mu += __shfl_xor(mu, o);
        mu *= (1.f/64.f);
        float d = y - mu, var = d*d;
        #pragma unroll
        for (int o = 1; o < 64; o <<= 1) var += __shfl_xor(var, o);
        var *= (1.f/64.f);
        float out = d * rsqrtf(var + LNEPS) * lng + lnb;
        out = out > 0.f ? out : 0.f;
        h[(size_t)v*64+lane] = out;
        ht16[(size_t)v*64+lane] = __float2half(dinv[v]*out);
    }
}

// ---------- readout ----------
__global__ __launch_bounds__(256) void k_readout(const float* __restrict__ h,
        const float* __restrict__ W1, const float* __restrict__ b1,
        const float* __restrict__ W2, const float* __restrict__ b2,
        float* __restrict__ out, int N){
    __shared__ float W1t[64*32];
    for (int idx = threadIdx.x; idx < 2048; idx += 256){
        int k = idx >> 5, j = idx & 31;
        W1t[idx] = W1[j*64+k];
    }
    __syncthreads();
    int lane = threadIdx.x & 63;
    float w2  = (lane < 32) ? W2[lane] : 0.f;
    float b1v = (lane < 32) ? b1[lane] : 0.f;
    float b2v = b2[0];
    int wid = (blockIdx.x*blockDim.x + threadIdx.x) >> 6;
    int nw  = (gridDim.x*blockDim.x) >> 6;
    for (int v = wid; v < N; v += nw){
        float hj = h[(size_t)v*64+lane];
        float acc = b1v;
        #pragma unroll
        for (int k = 0; k < 64; k++){
            float hk = __shfl(hj, k);
            if (lane < 32) acc += hk * W1t[k*32+lane];
        }
        float h1 = acc > 0.f ? acc : 0.f;
        float p = h1 * w2;
        #pragma unroll
        for (int o = 1; o < 32; o <<= 1) p += __shfl_xor(p, o);
        if (lane == 0){
            float z = p + b2v;
            out[v] = 1.f/(1.f + __expf(-z));
        }
    }
}

extern "C" void kernel_launch(void* const* d_in, const int* in_sizes, int n_in,
                              void* d_out, int out_size, void* d_ws, size_t ws_size,
                              hipStream_t stream){
    const ushort_t* xs = (const ushort_t*)d_in[0];
    const int*      ei = (const int*)d_in[1];

    int N = in_sizes[0] / 64;
    int E = in_sizes[1] / 2;
    const int* row = ei;
    const int* col = ei + E;

    float* f = (float*)d_ws;
    size_t o = 0;
    int*   flags = (int*)(f + o); o += 16;
    float* P     = f + o; o += P_TOTAL + 63;
    float* h     = f + o; o += (size_t)N*64;
    __half* ht16 = (__half*)(f + o); o += (size_t)N*32;
    __half* G16  = (__half*)(f + o); o += (size_t)N*32;
    __half* Aj16 = (__half*)(f + o); o += (size_t)N*32;
    __half* xg16 = (__half*)(f + o); o += (size_t)N*32;
    float* a_s   = f + o; o += (size_t)N*4;
    float* a_d   = f + o; o += (size_t)N*4;
    float* mxs   = f + o; o += 16;
    float* bmax_s= f + o; o += 1024;
    float* bmax_d= f + o; o += 1024;
    float* dinv  = f + o; o += (size_t)N;
    int* cnt     = (int*)(f + o); o += (size_t)2*N;
    int* tmp     = (int*)(f + o); o += (size_t)2*N;
    int* bsum    = (int*)(f + o); o += 256;
    int* ptr_r   = (int*)(f + o); o += (size_t)N + 1;
    int* ptr_c   = (int*)(f + o); o += (size_t)N + 1;
    int* nxt_r   = (int*)(f + o); o += (size_t)N;
    int* nxt_c   = (int*)(f + o); o += (size_t)N;
    int* re_col  = (int*)(f + o); o += (size_t)E;
    int* ce_row  = (int*)(f + o); o += (size_t)E;
    float* W1c   = f + o; o += 3*4096;
    float* b2c   = f + o; o += 3*64;

    const float* emb_W   = P + 0;
    const float* emb_b   = P + 4096;
    const float* e8_W    = P + 4160;
    const float* gat_W   = P + 16448;
    const float* att_src = P + 28736;
    const float* att_dst = P + 28928;
    const float* gat_b   = P + 29120;
    const float* fus_W   = P + 29312;
    const float* fus_b   = P + 53888;
    const float* ln_g    = P + 54080;
    const float* ln_b    = P + 54272;
    const float* r_W1    = P + 54464;
    const float* r_b1    = P + 56512;
    const float* r_W2    = P + 56544;
    const float* r_b2    = P + 56576;

    k_detect<<<1, 64, 0, stream>>>(d_in[0], d_in[2], d_in[4], d_in[5], d_in[6], d_in[7],
                                   d_in[9], d_in[13], d_in[15], d_in[11], flags);
    k_convert<<<(P_TOTAL+255)/256, 256, 0, stream>>>(
        d_in[2],d_in[3],d_in[4],d_in[5],d_in[6],d_in[7],d_in[8],d_in[9],
        d_in[10],d_in[11],d_in[12],d_in[13],d_in[14],d_in[15],d_in[16], flags, P);

    // CSR build
    int n2 = 2*N;
    int nb = (n2 + 1023) / 1024;
    hipMemsetAsync(cnt, 0, (size_t)n2*sizeof(int), stream);
    k_hist<<<(E+255)/256, 256, 0, stream>>>(row, col, cnt, N, E);
    k_scan1<<<nb, 1024, 0, stream>>>(cnt, tmp, bsum, n2);
    k_scan2<<<1, 256, 0, stream>>>(bsum, nb);
    k_scan3<<<(n2+255)/256, 256, 0, stream>>>(cnt, tmp, bsum, ptr_r, nxt_r, ptr_c, nxt_c,
                                              dinv, N, E);
    k_scatter<<<(E+255)/256, 256, 0, stream>>>(row, col, nxt_r, nxt_c, re_col, ce_row, E);

    k_prew<<<48, 256, 0, stream>>>(fus_W, e8_W, gat_b, fus_b, W1c, b2c);
    k_embed<<<1024, 256, 0, stream>>>(xs, flags, emb_W, emb_b, dinv, h, ht16, N);

    int ggrid = (N + 15) / 16;
    for (int i = 0; i < 3; i++){
        k_gat_g<<<1024, 256, 0, stream>>>(h, gat_W + (size_t)i*4096,
                                          att_src + i*64, att_dst + i*64,
                                          G16, a_s, a_d, N);
        k_headmax1<<<256, 256, 0, stream>>>(a_s, a_d, bmax_s, bmax_d, N*4);
        k_headmax2<<<1, 64, 0, stream>>>(bmax_s, bmax_d, mxs, 256);
        k_gather<<<ggrid, 256, 0, stream>>>(ht16, G16, a_s, a_d, mxs, dinv,
                                            ptr_r, re_col, ptr_c, ce_row,
                                            Aj16, xg16, N);
        k_fuse<<<1024, 256, 0, stream>>>(h, Aj16, xg16, dinv, ht16,
                                         W1c + i*4096, fus_W + (size_t)i*64*128, b2c + i*64,
                                         ln_g + i*64, ln_b + i*64, N);
    }
    k_readout<<<1024, 256, 0, stream>>>(h, r_W1, r_b1, r_W2, r_b2, (float*)d_out, N);
}

// Round 13
// 1723.746 us; speedup vs baseline: 2.5414x; 1.1865x over previous
//
#include <hip/hip_runtime.h>
#include <hip/hip_bf16.h>
#include <hip/hip_fp16.h>

typedef __hip_bfloat16 bf16;
typedef unsigned short ushort_t;
typedef unsigned short us8 __attribute__((ext_vector_type(8)));

#define NEG 0.2f
#define LNEPS 1e-5f
#define BWD 512                 // CSR bucket width (nodes)

__device__ __forceinline__ int plaus(unsigned int lo){
    lo &= 0x7FFFu;
    if (lo == 0) return 1;
    unsigned int ex = (lo >> 7) & 0xFF;
    return (ex >= 100 && ex <= 140) ? 1 : 0;
}

__device__ __forceinline__ float decode_slot(const ushort_t* s, long long i, int fl){
    long long base = i << fl;
    unsigned int hi = s[base + fl];
    unsigned int lo = s[base];
    unsigned int bits = (hi << 16) | (lo * (unsigned int)fl);
    return __uint_as_float(bits);
}

// ---------- per-tensor dtype flags ----------
__global__ void k_detect(const void* t0, const void* t1, const void* t2, const void* t3,
                         const void* t4, const void* t5, const void* t6, const void* t7,
                         const void* t8, const void* lng, int* flags){
    int t = threadIdx.x;
    if (blockIdx.x != 0) return;
    if (t < 9){
        const void* ptrs[9] = {t0,t1,t2,t3,t4,t5,t6,t7,t8};
        const ushort_t* w = (const ushort_t*)ptrs[t];
        int all_bf = 1;
        for (int i = 0; i < 16; i++) all_bf &= plaus((unsigned int)w[i]);
        flags[t] = all_bf ? 0 : 1;
    } else if (t == 9){
        const ushort_t* w = (const ushort_t*)lng;
        flags[9] = (w[0] == 0x3F80u) ? 0 : 1;
    }
}

// ---------- stage params ----------
#define P_TOTAL 56577
__global__ void k_convert(const void* p0, const void* p1, const void* p2, const void* p3,
        const void* p4, const void* p5, const void* p6, const void* p7, const void* p8,
        const void* p9, const void* p10, const void* p11, const void* p12, const void* p13,
        const void* p14, const int* flags, float* P){
    int idx = blockIdx.x*blockDim.x + threadIdx.x;
    if (idx >= P_TOTAL) return;
    const int sizes[15] = {4096,64,12288,12288,192,192,192,24576,192,192,192,2048,32,32,1};
    const int fidx[15]  = {1,  -1,  2,    3,    4,  5,  -1, 6,    -1, 9,  -1, 7,   -1,8, -1};
    const void* ptrs[15] = {p0,p1,p2,p3,p4,p5,p6,p7,p8,p9,p10,p11,p12,p13,p14};
    int s = 0, base = 0;
    while (idx - base >= sizes[s]){ base += sizes[s]; s++; }
    int li = idx - base;
    int fi = fidx[s];
    int fl = (fi >= 0) ? flags[fi] : 0;
    P[idx] = decode_slot((const ushort_t*)ptrs[s], li, fl);
}

// ---------- bucketed CSR build ----------
// bcnt[0..NBK) = row-side bucket counts ; bcnt[NBK..2NBK) = col-side
__global__ __launch_bounds__(1024) void kb_hist(const int* __restrict__ row,
        const int* __restrict__ col, int* __restrict__ bcnt, int NBK, int E){
    __shared__ int lh[512];
    int t = threadIdx.x;
    for (int i = t; i < 2*NBK; i += 1024) lh[i] = 0;
    __syncthreads();
    for (long long e = (long long)blockIdx.x*1024 + t; e < E; e += (long long)gridDim.x*1024){
        atomicAdd(&lh[row[e] >> 9], 1);
        atomicAdd(&lh[NBK + (col[e] >> 9)], 1);
    }
    __syncthreads();
    for (int i = t; i < 2*NBK; i += 1024){
        int v = lh[i];
        if (v) atomicAdd(&bcnt[i], v);
    }
}

__global__ __launch_bounds__(256) void kb_scan(const int* __restrict__ bcnt,
        int* __restrict__ bptr_r, int* __restrict__ bptr_c,
        int* __restrict__ bcur_r, int* __restrict__ bcur_c, int NBK, int E){
    __shared__ int sh[256];
    int side = blockIdx.x;
    const int* c = bcnt + side*NBK;
    int* bp = side ? bptr_c : bptr_r;
    int* bc = side ? bcur_c : bcur_r;
    int t = threadIdx.x;
    int v = (t < NBK) ? c[t] : 0;
    sh[t] = v; __syncthreads();
    for (int off = 1; off < 256; off <<= 1){
        int add = (t >= off) ? sh[t-off] : 0;
        __syncthreads();
        sh[t] += add;
        __syncthreads();
    }
    if (t < NBK){ int e = sh[t] - v; bp[t] = e; bc[t] = e; }
    if (t == 0) bp[NBK] = E;
}

__global__ __launch_bounds__(1024) void kb_bin(const int* __restrict__ key,
        const int* __restrict__ pay, int* __restrict__ bcur,
        uint2* __restrict__ stage, int NBK, int E){
    __shared__ int lh[256], lbase[256];
    int t = threadIdx.x;
    for (long long tile = (long long)blockIdx.x*1024; tile < E; tile += (long long)gridDim.x*1024){
        for (int i = t; i < NBK; i += 1024) lh[i] = 0;
        __syncthreads();
        int e = (int)tile + t;
        int k = 0, p = 0, b = -1, rank = 0;
        if (e < E){
            k = key[e]; p = pay[e]; b = k >> 9;
            rank = atomicAdd(&lh[b], 1);
        }
        __syncthreads();
        for (int i = t; i < NBK; i += 1024){
            int c = lh[i];
            lbase[i] = c ? atomicAdd(&bcur[i], c) : 0;
        }
        __syncthreads();
        if (b >= 0) stage[lbase[b] + rank] = make_uint2((unsigned)k, (unsigned)p);
        __syncthreads();
    }
}

__global__ __launch_bounds__(1024) void kb_place(const uint2* __restrict__ stage,
        const int* __restrict__ bptr, int* __restrict__ ptr, int* __restrict__ outarr,
        float* __restrict__ dinv, int wantdinv, int N, int E){
    __shared__ int lcnt[BWD], lsc[BWD], lcur[BWD];
    int b = blockIdx.x;
    int s = bptr[b], e = bptr[b+1];
    int nbase = b << 9;
    int t = threadIdx.x;
    if (t < BWD) lcnt[t] = 0;
    __syncthreads();
    for (int i = s + t; i < e; i += 1024)
        atomicAdd(&lcnt[stage[i].x - nbase], 1);
    __syncthreads();
    if (t < BWD) lsc[t] = lcnt[t];
    __syncthreads();
    for (int off = 1; off < BWD; off <<= 1){
        int add = (t >= off && t < BWD) ? lsc[t-off] : 0;
        __syncthreads();
        if (t < BWD) lsc[t] += add;
        __syncthreads();
    }
    if (t < BWD){
        int node = nbase + t;
        int excl = lsc[t] - lcnt[t];
        lcur[t] = excl;
        if (node < N){
            ptr[node] = s + excl;
            if (wantdinv) dinv[node] = lcnt[t] > 0 ? rsqrtf((float)lcnt[t]) : 0.f;
        }
    }
    if (b == 0 && t == 0) ptr[N] = E;
    __syncthreads();
    for (int i = s + t; i < e; i += 1024){
        uint2 rec = stage[i];
        int pos = s + atomicAdd(&lcur[rec.x - nbase], 1);
        outarr[pos] = (int)rec.y;
    }
}

// ---------- precompute fused weights ----------
__global__ void k_prew(const float* __restrict__ fus_W, const float* __restrict__ e8_W,
                       const float* __restrict__ gat_b, const float* __restrict__ fus_b,
                       float* __restrict__ W1c, float* __restrict__ b2c){
    int t = blockIdx.x*blockDim.x + threadIdx.x;
    if (t < 3*4096){
        int i = t >> 12, jq = t & 4095, j = jq >> 6, q = jq & 63;
        const float* fw = fus_W + (size_t)i*64*128 + (size_t)j*128;
        const float* ew = e8_W + (size_t)i*4096;
        float acc = 0.f;
        for (int p = 0; p < 64; p++) acc += fw[p] * ew[p*64+q];
        W1c[t] = acc;
    }
    if (t < 3*64){
        int i = t >> 6, j = t & 63;
        const float* fw = fus_W + (size_t)i*64*128 + (size_t)j*128 + 64;
        float acc = fus_b[i*64+j];
        for (int p = 0; p < 64; p++) acc += gat_b[i*64+p] * fw[p];
        b2c[t] = acc;
    }
}

// ---------- embedding: h fp32 + ht16 = dinv*h ----------
__global__ __launch_bounds__(256) void k_embed(const ushort_t* __restrict__ xs,
        const int* __restrict__ flags, const float* __restrict__ W,
        const float* __restrict__ b, const float* __restrict__ dinv,
        float* __restrict__ h, __half* __restrict__ ht16, int N){
    __shared__ float Wt[64*64];
    for (int idx = threadIdx.x; idx < 4096; idx += 256){
        int k = idx >> 6, j = idx & 63;
        Wt[idx] = W[j*64+k];
    }
    __syncthreads();
    int fl = flags[0];
    int lane = threadIdx.x & 63;
    int wid  = (blockIdx.x*blockDim.x + threadIdx.x) >> 6;
    int nw   = (gridDim.x*blockDim.x) >> 6;
    float bj = b[lane];
    for (int v = wid; v < N; v += nw){
        float xj = decode_slot(xs, (long long)v*64 + lane, fl);
        float acc = bj;
        #pragma unroll
        for (int k = 0; k < 64; k++) acc += __shfl(xj, k) * Wt[k*64+lane];
        h[(size_t)v*64 + lane] = acc;
        ht16[(size_t)v*64 + lane] = __float2half(dinv[v]*acc);
    }
}

// ---------- per-layer: G16 = h @ gat_W (fp16), head sums ----------
__global__ __launch_bounds__(256) void k_gat_g(const float* __restrict__ h,
        const float* __restrict__ gatW, const float* __restrict__ att_src,
        const float* __restrict__ att_dst, __half* __restrict__ G16,
        float* __restrict__ a_s, float* __restrict__ a_d, int N){
    __shared__ float Ws[64*64];
    for (int idx = threadIdx.x; idx < 4096; idx += 256) Ws[idx] = gatW[idx];
    __syncthreads();
    int lane = threadIdx.x & 63, hh = lane >> 4;
    float asrc = att_src[lane];
    float adst = att_dst[lane];
    int wid = (blockIdx.x*blockDim.x + threadIdx.x) >> 6;
    int nw  = (gridDim.x*blockDim.x) >> 6;
    for (int v = wid; v < N; v += nw){
        float hj = h[(size_t)v*64 + lane];
        float g = 0.f;
        #pragma unroll
        for (int k = 0; k < 64; k++) g += __shfl(hj, k) * Ws[k*64+lane];
        G16[(size_t)v*64 + lane] = __float2half(g);
        float ts = g*asrc, td = g*adst;
        #pragma unroll
        for (int o = 1; o < 16; o <<= 1){ ts += __shfl_xor(ts, o); td += __shfl_xor(td, o); }
        if ((lane & 15) == 0){
            a_s[v*4+hh] = ts; a_d[v*4+hh] = td;
        }
    }
}

// ---------- per-head global maxes ----------
__global__ __launch_bounds__(256) void k_headmax1(const float* __restrict__ a_s,
        const float* __restrict__ a_d, float* __restrict__ bmax_s,
        float* __restrict__ bmax_d, int n4){
    __shared__ float shs[256], shd[256];
    int t = threadIdx.x;
    int S = gridDim.x * 256;
    float ms = -1e30f, md = -1e30f;
    for (int i = blockIdx.x*256 + t; i < n4; i += S){
        ms = fmaxf(ms, a_s[i]); md = fmaxf(md, a_d[i]);
    }
    shs[t] = ms; shd[t] = md; __syncthreads();
    for (int off = 128; off >= 4; off >>= 1){
        if (t < off){ shs[t] = fmaxf(shs[t], shs[t+off]); shd[t] = fmaxf(shd[t], shd[t+off]); }
        __syncthreads();
    }
    if (t < 4){ bmax_s[blockIdx.x*4+t] = shs[t]; bmax_d[blockIdx.x*4+t] = shd[t]; }
}
__global__ void k_headmax2(const float* __restrict__ bmax_s, const float* __restrict__ bmax_d,
                           float* __restrict__ mxs, int nb){
    int t = threadIdx.x;
    if (blockIdx.x != 0 || t >= 8) return;
    const float* src = (t < 4) ? bmax_s : bmax_d;
    int hh = t & 3;
    float m = -1e30f;
    for (int i = 0; i < nb; i++) m = fmaxf(m, src[i*4+hh]);
    mxs[t] = m;
}

__device__ __forceinline__ float leaky(float t){ return t > 0.f ? t : NEG*t; }

// ---------- gather: 8 nodes/wave, 8 lanes/node, 16B loads ----------
__global__ __launch_bounds__(256) void k_gather(const __half* __restrict__ ht16,
        const __half* __restrict__ G16,
        const float* __restrict__ a_s, const float* __restrict__ a_d,
        const float* __restrict__ mxs, const float* __restrict__ dinv,
        const int* __restrict__ row_ptr, const int* __restrict__ re_col,
        const int* __restrict__ col_ptr, const int* __restrict__ ce_row,
        __half* __restrict__ Aj16, __half* __restrict__ xg16, int N){
    int lane = threadIdx.x & 63;
    int grp  = lane >> 3;                 // node within wave
    int sub  = lane & 7;                  // 8-ch slot
    int hh   = sub >> 1;                  // head for these 8 channels
    int wid  = (blockIdx.x*blockDim.x + threadIdx.x) >> 6;
    int v    = wid*8 + grp;
    if (v >= N) return;
    const us8* htb = (const us8*)ht16;
    const us8* gb  = (const us8*)G16;
    float sh = leaky(mxs[hh] + mxs[4+hh]);
    // --- e8: Aj = dinv[v] * sum ht16[c] ---
    int rs = row_ptr[v], re = row_ptr[v+1];
    float a0[8] = {0,0,0,0,0,0,0,0}, a1[8] = {0,0,0,0,0,0,0,0};
    float a2[8] = {0,0,0,0,0,0,0,0}, a3[8] = {0,0,0,0,0,0,0,0};
    int i = rs;
    for (; i + 3 < re; i += 4){
        us8 q0 = htb[(size_t)re_col[i]*8 + sub];
        us8 q1 = htb[(size_t)re_col[i+1]*8 + sub];
        us8 q2 = htb[(size_t)re_col[i+2]*8 + sub];
        us8 q3 = htb[(size_t)re_col[i+3]*8 + sub];
        #pragma unroll
        for (int j = 0; j < 8; j++){
            a0[j] += __half2float(__ushort_as_half(q0[j]));
            a1[j] += __half2float(__ushort_as_half(q1[j]));
            a2[j] += __half2float(__ushort_as_half(q2[j]));
            a3[j] += __half2float(__ushort_as_half(q3[j]));
        }
    }
    for (; i < re; i++){
        us8 q0 = htb[(size_t)re_col[i]*8 + sub];
        #pragma unroll
        for (int j = 0; j < 8; j++) a0[j] += __half2float(__ushort_as_half(q0[j]));
    }
    float dv = dinv[v];
    us8 pa;
    #pragma unroll
    for (int j = 0; j < 8; j++)
        pa[j] = __half_as_ushort(__float2half(dv*((a0[j]+a1[j]) + (a2[j]+a3[j]))));
    ((us8*)Aj16)[(size_t)v*8 + sub] = pa;
    // --- GAT: global-shift softmax gather ---
    float adv = a_d[v*4+hh];
    float eesl = __expf(leaky(a_s[v*4+hh] + adv) - sh);
    float s0 = eesl, s1 = 0.f, s2 = 0.f, s3 = 0.f;
    {
        us8 g0 = gb[(size_t)v*8 + sub];
        #pragma unroll
        for (int j = 0; j < 8; j++){
            a0[j] = eesl * __half2float(__ushort_as_half(g0[j]));
            a1[j] = 0.f; a2[j] = 0.f; a3[j] = 0.f;
        }
    }
    int cs = col_ptr[v], ce = col_ptr[v+1];
    i = cs;
    for (; i + 3 < ce; i += 4){
        int r0 = ce_row[i], r1 = ce_row[i+1], r2 = ce_row[i+2], r3 = ce_row[i+3];
        float e0 = __expf(leaky(a_s[r0*4+hh] + adv) - sh);
        float e1 = __expf(leaky(a_s[r1*4+hh] + adv) - sh);
        float e2 = __expf(leaky(a_s[r2*4+hh] + adv) - sh);
        float e3 = __expf(leaky(a_s[r3*4+hh] + adv) - sh);
        us8 q0 = gb[(size_t)r0*8 + sub];
        us8 q1 = gb[(size_t)r1*8 + sub];
        us8 q2 = gb[(size_t)r2*8 + sub];
        us8 q3 = gb[(size_t)r3*8 + sub];
        #pragma unroll
        for (int j = 0; j < 8; j++){
            a0[j] += e0 * __half2float(__ushort_as_half(q0[j]));
            a1[j] += e1 * __half2float(__ushort_as_half(q1[j]));
            a2[j] += e2 * __half2float(__ushort_as_half(q2[j]));
            a3[j] += e3 * __half2float(__ushort_as_half(q3[j]));
        }
        s0 += e0; s1 += e1; s2 += e2; s3 += e3;
    }
    for (; i < ce; i++){
        int r0 = ce_row[i];
        float e0 = __expf(leaky(a_s[r0*4+hh] + adv) - sh);
        us8 q0 = gb[(size_t)r0*8 + sub];
        #pragma unroll
        for (int j = 0; j < 8; j++) a0[j] += e0 * __half2float(__ushort_as_half(q0[j]));
        s0 += e0;
    }
    float inv = 1.f/((s0+s1)+(s2+s3));
    us8 px;
    #pragma unroll
    for (int j = 0; j < 8; j++)
        px[j] = __half_as_ushort(__float2half(((a0[j]+a1[j]) + (a2[j]+a3[j]))*inv));
    ((us8*)xg16)[(size_t)v*8 + sub] = px;
}

// ---------- fuse: matmuls + residual + LN + ReLU, in-place h ----------
__global__ __launch_bounds__(256) void k_fuse(float* __restrict__ h,
        const __half* __restrict__ Aj16, const __half* __restrict__ xg16,
        const float* __restrict__ dinv, __half* __restrict__ ht16,
        const float* __restrict__ W1c, const float* __restrict__ fus_W,
        const float* __restrict__ b2c, const float* __restrict__ ln_g,
        const float* __restrict__ ln_b, int N){
    __shared__ float WT1[64*64];
    __shared__ float WT2[64*64];
    for (int idx = threadIdx.x; idx < 4096; idx += 256){
        int a0 = idx >> 6, j = idx & 63;
        WT1[idx] = W1c[j*64 + a0];
        WT2[idx] = fus_W[j*128 + 64 + a0];
    }
    __syncthreads();
    int lane = threadIdx.x & 63;
    float lng = ln_g[lane], lnb = ln_b[lane];
    float bj = b2c[lane];
    int wid = (blockIdx.x*blockDim.x + threadIdx.x) >> 6;
    int nw  = (gridDim.x*blockDim.x) >> 6;
    for (int v = wid; v < N; v += nw){
        float Aj = __half2float(Aj16[(size_t)v*64 + lane]);
        float xg = __half2float(xg16[(size_t)v*64 + lane]);
        float y = bj + h[(size_t)v*64 + lane];
        #pragma unroll
        for (int q = 0; q < 64; q++) y += __shfl(Aj, q) * WT1[q*64+lane];
        #pragma unroll
        for (int p = 0; p < 64; p++) y += __shfl(xg, p) * WT2[p*64+lane];
        float mu = y;
        #pragma unroll
        for (int o = 1; o < 64; o <<= 1) mu += __shfl_xor(mu, o);
        mu *= (1.f/64.f);
        float d = y - mu, var = d*d;
        #pragma unroll
        for (int o = 1; o < 64; o <<= 1) var += __shfl_xor(var, o);
        var *= (1.f/64.f);
        float out = d * rsqrtf(var + LNEPS) * lng + lnb;
        out = out > 0.f ? out : 0.f;
        h[(size_t)v*64+lane] = out;
        ht16[(size_t)v*64+lane] = __float2half(dinv[v]*out);
    }
}

// ---------- readout ----------
__global__ __launch_bounds__(256) void k_readout(const float* __restrict__ h,
        const float* __restrict__ W1, const float* __restrict__ b1,
        const float* __restrict__ W2, const float* __restrict__ b2,
        float* __restrict__ out, int N){
    __shared__ float W1t[64*32];
    for (int idx = threadIdx.x; idx < 2048; idx += 256){
        int k = idx >> 5, j = idx & 31;
        W1t[idx] = W1[j*64+k];
    }
    __syncthreads();
    int lane = threadIdx.x & 63;
    float w2  = (lane < 32) ? W2[lane] : 0.f;
    float b1v = (lane < 32) ? b1[lane] : 0.f;
    float b2v = b2[0];
    int wid = (blockIdx.x*blockDim.x + threadIdx.x) >> 6;
    int nw  = (gridDim.x*blockDim.x) >> 6;
    for (int v = wid; v < N; v += nw){
        float hj = h[(size_t)v*64+lane];
        float acc = b1v;
        #pragma unroll
        for (int k = 0; k < 64; k++){
            float hk = __shfl(hj, k);
            if (lane < 32) acc += hk * W1t[k*32+lane];
        }
        float h1 = acc > 0.f ? acc : 0.f;
        float p = h1 * w2;
        #pragma unroll
        for (int o = 1; o < 32; o <<= 1) p += __shfl_xor(p, o);
        if (lane == 0){
            float z = p + b2v;
            out[v] = 1.f/(1.f + __expf(-z));
        }
    }
}

extern "C" void kernel_launch(void* const* d_in, const int* in_sizes, int n_in,
                              void* d_out, int out_size, void* d_ws, size_t ws_size,
                              hipStream_t stream){
    const ushort_t* xs = (const ushort_t*)d_in[0];
    const int*      ei = (const int*)d_in[1];

    int N = in_sizes[0] / 64;
    int E = in_sizes[1] / 2;
    const int* row = ei;
    const int* col = ei + E;
    int NBK = (N + BWD - 1) / BWD;       // <= 256 assumed (N <= 131072)

    size_t stageF = (size_t)2*E;                    // uint2 stage in float units
    size_t mirF   = (size_t)N*32;                   // N*64 fp16 in float units
    size_t aliasF = stageF > mirF ? stageF : mirF;

    float* f = (float*)d_ws;
    size_t o = 0;
    int*   flags = (int*)(f + o); o += 16;
    float* P     = f + o; o += P_TOTAL + 63;
    float* h     = f + o; o += (size_t)N*64;
    __half* ht16 = (__half*)(f + o); o += mirF;
    __half* G16  = (__half*)(f + o); o += mirF;
    __half* Aj16 = (__half*)(f + o); size_t aoff = o; o += aliasF;
    __half* xg16 = (__half*)(f + o); size_t xoff = o; o += aliasF;
    uint2* stage_r = (uint2*)(f + aoff);
    uint2* stage_c = (uint2*)(f + xoff);
    float* a_s   = f + o; o += (size_t)N*4;
    float* a_d   = f + o; o += (size_t)N*4;
    float* mxs   = f + o; o += 16;
    float* bmax_s= f + o; o += 1024;
    float* bmax_d= f + o; o += 1024;
    float* dinv  = f + o; o += ((size_t)N + 15) & ~15ull;
    int* bcnt    = (int*)(f + o); o += 512;
    int* bptr_r  = (int*)(f + o); o += 512;
    int* bptr_c  = (int*)(f + o); o += 512;
    int* bcur_r  = (int*)(f + o); o += 512;
    int* bcur_c  = (int*)(f + o); o += 512;
    int* ptr_r   = (int*)(f + o); o += ((size_t)N + 16) & ~15ull;
    int* ptr_c   = (int*)(f + o); o += ((size_t)N + 16) & ~15ull;
    int* re_col  = (int*)(f + o); o += (size_t)E;
    int* ce_row  = (int*)(f + o); o += (size_t)E;
    float* W1c   = f + o; o += 3*4096;
    float* b2c   = f + o; o += 3*64;

    const float* emb_W   = P + 0;
    const float* emb_b   = P + 4096;
    const float* e8_W    = P + 4160;
    const float* gat_W   = P + 16448;
    const float* att_src = P + 28736;
    const float* att_dst = P + 28928;
    const float* gat_b   = P + 29120;
    const float* fus_W   = P + 29312;
    const float* fus_b   = P + 53888;
    const float* ln_g    = P + 54080;
    const float* ln_b    = P + 54272;
    const float* r_W1    = P + 54464;
    const float* r_b1    = P + 56512;
    const float* r_W2    = P + 56544;
    const float* r_b2    = P + 56576;

    k_detect<<<1, 64, 0, stream>>>(d_in[0], d_in[2], d_in[4], d_in[5], d_in[6], d_in[7],
                                   d_in[9], d_in[13], d_in[15], d_in[11], flags);
    k_convert<<<(P_TOTAL+255)/256, 256, 0, stream>>>(
        d_in[2],d_in[3],d_in[4],d_in[5],d_in[6],d_in[7],d_in[8],d_in[9],
        d_in[10],d_in[11],d_in[12],d_in[13],d_in[14],d_in[15],d_in[16], flags, P);

    // bucketed CSR build
    hipMemsetAsync(bcnt, 0, 512*sizeof(int), stream);
    kb_hist<<<256, 1024, 0, stream>>>(row, col, bcnt, NBK, E);
    kb_scan<<<2, 256, 0, stream>>>(bcnt, bptr_r, bptr_c, bcur_r, bcur_c, NBK, E);
    kb_bin<<<256, 1024, 0, stream>>>(row, col, bcur_r, stage_r, NBK, E);
    kb_bin<<<256, 1024, 0, stream>>>(col, row, bcur_c, stage_c, NBK, E);
    kb_place<<<NBK, 1024, 0, stream>>>(stage_r, bptr_r, ptr_r, re_col, dinv, 0, N, E);
    kb_place<<<NBK, 1024, 0, stream>>>(stage_c, bptr_c, ptr_c, ce_row, dinv, 1, N, E);

    k_prew<<<48, 256, 0, stream>>>(fus_W, e8_W, gat_b, fus_b, W1c, b2c);
    k_embed<<<1024, 256, 0, stream>>>(xs, flags, emb_W, emb_b, dinv, h, ht16, N);

    int ggrid = (N + 31) / 32;
    for (int i = 0; i < 3; i++){
        k_gat_g<<<1024, 256, 0, stream>>>(h, gat_W + (size_t)i*4096,
                                          att_src + i*64, att_dst + i*64,
                                          G16, a_s, a_d, N);
        k_headmax1<<<256, 256, 0, stream>>>(a_s, a_d, bmax_s, bmax_d, N*4);
        k_headmax2<<<1, 64, 0, stream>>>(bmax_s, bmax_d, mxs, 256);
        k_gather<<<ggrid, 256, 0, stream>>>(ht16, G16, a_s, a_d, mxs, dinv,
                                            ptr_r, re_col, ptr_c, ce_row,
                                            Aj16, xg16, N);
        k_fuse<<<1024, 256, 0, stream>>>(h, Aj16, xg16, dinv, ht16,
                                         W1c + i*4096, fus_W + (size_t)i*64*128, b2c + i*64,
                                         ln_g + i*64, ln_b + i*64, N);
    }
    k_readout<<<1024, 256, 0, stream>>>(h, r_W1, r_b1, r_W2, r_b2, (float*)d_out, N);
}

// Round 14
// 1142.164 us; speedup vs baseline: 3.8355x; 1.5092x over previous
//
#include <hip/hip_runtime.h>
#include <hip/hip_bf16.h>
#include <hip/hip_fp16.h>

typedef __hip_bfloat16 bf16;
typedef unsigned short ushort_t;
typedef unsigned short us8 __attribute__((ext_vector_type(8)));
typedef _Float16 half8 __attribute__((ext_vector_type(8)));
typedef float f32x4 __attribute__((ext_vector_type(4)));

#define NEG 0.2f
#define LNEPS 1e-5f
#define BWD 512                 // CSR bucket width (nodes)

__device__ __forceinline__ int plaus(unsigned int lo){
    lo &= 0x7FFFu;
    if (lo == 0) return 1;
    unsigned int ex = (lo >> 7) & 0xFF;
    return (ex >= 100 && ex <= 140) ? 1 : 0;
}

__device__ __forceinline__ float decode_slot(const ushort_t* s, long long i, int fl){
    long long base = i << fl;
    unsigned int hi = s[base + fl];
    unsigned int lo = s[base];
    unsigned int bits = (hi << 16) | (lo * (unsigned int)fl);
    return __uint_as_float(bits);
}

// ---------- per-tensor dtype flags ----------
__global__ void k_detect(const void* t0, const void* t1, const void* t2, const void* t3,
                         const void* t4, const void* t5, const void* t6, const void* t7,
                         const void* t8, const void* lng, int* flags){
    int t = threadIdx.x;
    if (blockIdx.x != 0) return;
    if (t < 9){
        const void* ptrs[9] = {t0,t1,t2,t3,t4,t5,t6,t7,t8};
        const ushort_t* w = (const ushort_t*)ptrs[t];
        int all_bf = 1;
        for (int i = 0; i < 16; i++) all_bf &= plaus((unsigned int)w[i]);
        flags[t] = all_bf ? 0 : 1;
    } else if (t == 9){
        const ushort_t* w = (const ushort_t*)lng;
        flags[9] = (w[0] == 0x3F80u) ? 0 : 1;
    }
}

// ---------- stage params ----------
#define P_TOTAL 56577
__global__ void k_convert(const void* p0, const void* p1, const void* p2, const void* p3,
        const void* p4, const void* p5, const void* p6, const void* p7, const void* p8,
        const void* p9, const void* p10, const void* p11, const void* p12, const void* p13,
        const void* p14, const int* flags, float* P){
    int idx = blockIdx.x*blockDim.x + threadIdx.x;
    if (idx >= P_TOTAL) return;
    const int sizes[15] = {4096,64,12288,12288,192,192,192,24576,192,192,192,2048,32,32,1};
    const int fidx[15]  = {1,  -1,  2,    3,    4,  5,  -1, 6,    -1, 9,  -1, 7,   -1,8, -1};
    const void* ptrs[15] = {p0,p1,p2,p3,p4,p5,p6,p7,p8,p9,p10,p11,p12,p13,p14};
    int s = 0, base = 0;
    while (idx - base >= sizes[s]){ base += sizes[s]; s++; }
    int li = idx - base;
    int fi = fidx[s];
    int fl = (fi >= 0) ? flags[fi] : 0;
    P[idx] = decode_slot((const ushort_t*)ptrs[s], li, fl);
}

// ---------- bucketed CSR build ----------
__global__ __launch_bounds__(1024) void kb_hist(const int* __restrict__ row,
        const int* __restrict__ col, int* __restrict__ bcnt, int NBK, int E){
    __shared__ int lh[512];
    int t = threadIdx.x;
    for (int i = t; i < 2*NBK; i += 1024) lh[i] = 0;
    __syncthreads();
    for (long long e = (long long)blockIdx.x*1024 + t; e < E; e += (long long)gridDim.x*1024){
        atomicAdd(&lh[row[e] >> 9], 1);
        atomicAdd(&lh[NBK + (col[e] >> 9)], 1);
    }
    __syncthreads();
    for (int i = t; i < 2*NBK; i += 1024){
        int v = lh[i];
        if (v) atomicAdd(&bcnt[i], v);
    }
}

__global__ __launch_bounds__(256) void kb_scan(const int* __restrict__ bcnt,
        int* __restrict__ bptr_r, int* __restrict__ bptr_c,
        int* __restrict__ bcur_r, int* __restrict__ bcur_c, int NBK, int E){
    __shared__ int sh[256];
    int side = blockIdx.x;
    const int* c = bcnt + side*NBK;
    int* bp = side ? bptr_c : bptr_r;
    int* bc = side ? bcur_c : bcur_r;
    int t = threadIdx.x;
    int v = (t < NBK) ? c[t] : 0;
    sh[t] = v; __syncthreads();
    for (int off = 1; off < 256; off <<= 1){
        int add = (t >= off) ? sh[t-off] : 0;
        __syncthreads();
        sh[t] += add;
        __syncthreads();
    }
    if (t < NBK){ int e = sh[t] - v; bp[t] = e; bc[t] = e; }
    if (t == 0) bp[NBK] = E;
}

__global__ __launch_bounds__(1024) void kb_bin(const int* __restrict__ key,
        const int* __restrict__ pay, int* __restrict__ bcur,
        uint2* __restrict__ stage, int NBK, int E){
    __shared__ int lh[256], lbase[256];
    int t = threadIdx.x;
    for (long long tile = (long long)blockIdx.x*1024; tile < E; tile += (long long)gridDim.x*1024){
        for (int i = t; i < NBK; i += 1024) lh[i] = 0;
        __syncthreads();
        int e = (int)tile + t;
        int k = 0, p = 0, b = -1, rank = 0;
        if (e < E){
            k = key[e]; p = pay[e]; b = k >> 9;
            rank = atomicAdd(&lh[b], 1);
        }
        __syncthreads();
        for (int i = t; i < NBK; i += 1024){
            int c = lh[i];
            lbase[i] = c ? atomicAdd(&bcur[i], c) : 0;
        }
        __syncthreads();
        if (b >= 0) stage[lbase[b] + rank] = make_uint2((unsigned)k, (unsigned)p);
        __syncthreads();
    }
}

__global__ __launch_bounds__(1024) void kb_place(const uint2* __restrict__ stage,
        const int* __restrict__ bptr, int* __restrict__ ptr, int* __restrict__ outarr,
        float* __restrict__ dinv, int wantdinv, int N, int E){
    __shared__ int lcnt[BWD], lsc[BWD], lcur[BWD];
    int b = blockIdx.x;
    int s = bptr[b], e = bptr[b+1];
    int nbase = b << 9;
    int t = threadIdx.x;
    if (t < BWD) lcnt[t] = 0;
    __syncthreads();
    for (int i = s + t; i < e; i += 1024)
        atomicAdd(&lcnt[stage[i].x - nbase], 1);
    __syncthreads();
    if (t < BWD) lsc[t] = lcnt[t];
    __syncthreads();
    for (int off = 1; off < BWD; off <<= 1){
        int add = (t >= off && t < BWD) ? lsc[t-off] : 0;
        __syncthreads();
        if (t < BWD) lsc[t] += add;
        __syncthreads();
    }
    if (t < BWD){
        int node = nbase + t;
        int excl = lsc[t] - lcnt[t];
        lcur[t] = excl;
        if (node < N){
            ptr[node] = s + excl;
            if (wantdinv) dinv[node] = lcnt[t] > 0 ? rsqrtf((float)lcnt[t]) : 0.f;
        }
    }
    if (b == 0 && t == 0) ptr[N] = E;
    __syncthreads();
    for (int i = s + t; i < e; i += 1024){
        uint2 rec = stage[i];
        int pos = s + atomicAdd(&lcur[rec.x - nbase], 1);
        outarr[pos] = (int)rec.y;
    }
}

// ---------- precompute fused weights ----------
__global__ void k_prew(const float* __restrict__ fus_W, const float* __restrict__ e8_W,
                       const float* __restrict__ gat_b, const float* __restrict__ fus_b,
                       float* __restrict__ W1c, float* __restrict__ b2c){
    int t = blockIdx.x*blockDim.x + threadIdx.x;
    if (t < 3*4096){
        int i = t >> 12, jq = t & 4095, j = jq >> 6, q = jq & 63;
        const float* fw = fus_W + (size_t)i*64*128 + (size_t)j*128;
        const float* ew = e8_W + (size_t)i*4096;
        float acc = 0.f;
        for (int p = 0; p < 64; p++) acc += fw[p] * ew[p*64+q];
        W1c[t] = acc;
    }
    if (t < 3*64){
        int i = t >> 6, j = t & 63;
        const float* fw = fus_W + (size_t)i*64*128 + (size_t)j*128 + 64;
        float acc = fus_b[i*64+j];
        for (int p = 0; p < 64; p++) acc += gat_b[i*64+p] * fw[p];
        b2c[t] = acc;
    }
}

// ---------- pre-swizzle fusion weights into MFMA B-fragment order (fp16) ----------
// Bfrag[i][((t*4+kk)*64+lane)*8+j] = W[k=kk*32+(lane>>4)*8+j][n=t*16+(lane&15)]
// where W[k][n] = k<64 ? W1c[i][n*64+k] : fus_W[i][n*128+64+(k-64)]
__global__ void k_prewB(const float* __restrict__ W1c, const float* __restrict__ fus_W,
                        _Float16* __restrict__ Bfrag){
    int idx = blockIdx.x*blockDim.x + threadIdx.x;
    if (idx >= 3*8192) return;
    int i = idx / 8192; int rem = idx & 8191;
    int j = rem & 7, lane = (rem >> 3) & 63, kk = (rem >> 9) & 3, t = rem >> 11;
    int k = kk*32 + (lane >> 4)*8 + j;
    int n = t*16 + (lane & 15);
    float v = (k < 64) ? W1c[i*4096 + n*64 + k]
                       : fus_W[(size_t)i*8192 + n*128 + 64 + (k - 64)];
    Bfrag[idx] = (_Float16)v;
}

// ---------- embedding: h fp32 + ht16 = dinv*h ----------
__global__ __launch_bounds__(256) void k_embed(const ushort_t* __restrict__ xs,
        const int* __restrict__ flags, const float* __restrict__ W,
        const float* __restrict__ b, const float* __restrict__ dinv,
        float* __restrict__ h, __half* __restrict__ ht16, int N){
    __shared__ float Wt[64*64];
    for (int idx = threadIdx.x; idx < 4096; idx += 256){
        int k = idx >> 6, j = idx & 63;
        Wt[idx] = W[j*64+k];
    }
    __syncthreads();
    int fl = flags[0];
    int lane = threadIdx.x & 63;
    int wid  = (blockIdx.x*blockDim.x + threadIdx.x) >> 6;
    int nw   = (gridDim.x*blockDim.x) >> 6;
    float bj = b[lane];
    for (int v = wid; v < N; v += nw){
        float xj = decode_slot(xs, (long long)v*64 + lane, fl);
        float acc = bj;
        #pragma unroll
        for (int k = 0; k < 64; k++) acc += __shfl(xj, k) * Wt[k*64+lane];
        h[(size_t)v*64 + lane] = acc;
        ht16[(size_t)v*64 + lane] = __float2half(dinv[v]*acc);
    }
}

// ---------- per-layer: G16 = h @ gat_W (fp16), head sums ----------
__global__ __launch_bounds__(256) void k_gat_g(const float* __restrict__ h,
        const float* __restrict__ gatW, const float* __restrict__ att_src,
        const float* __restrict__ att_dst, __half* __restrict__ G16,
        float* __restrict__ a_s, float* __restrict__ a_d, int N){
    __shared__ float Ws[64*64];
    for (int idx = threadIdx.x; idx < 4096; idx += 256) Ws[idx] = gatW[idx];
    __syncthreads();
    int lane = threadIdx.x & 63, hh = lane >> 4;
    float asrc = att_src[lane];
    float adst = att_dst[lane];
    int wid = (blockIdx.x*blockDim.x + threadIdx.x) >> 6;
    int nw  = (gridDim.x*blockDim.x) >> 6;
    for (int v = wid; v < N; v += nw){
        float hj = h[(size_t)v*64 + lane];
        float g = 0.f;
        #pragma unroll
        for (int k = 0; k < 64; k++) g += __shfl(hj, k) * Ws[k*64+lane];
        G16[(size_t)v*64 + lane] = __float2half(g);
        float ts = g*asrc, td = g*adst;
        #pragma unroll
        for (int o = 1; o < 16; o <<= 1){ ts += __shfl_xor(ts, o); td += __shfl_xor(td, o); }
        if ((lane & 15) == 0){
            a_s[v*4+hh] = ts; a_d[v*4+hh] = td;
        }
    }
}

// ---------- per-head global maxes ----------
__global__ __launch_bounds__(256) void k_headmax1(const float* __restrict__ a_s,
        const float* __restrict__ a_d, float* __restrict__ bmax_s,
        float* __restrict__ bmax_d, int n4){
    __shared__ float shs[256], shd[256];
    int t = threadIdx.x;
    int S = gridDim.x * 256;
    float ms = -1e30f, md = -1e30f;
    for (int i = blockIdx.x*256 + t; i < n4; i += S){
        ms = fmaxf(ms, a_s[i]); md = fmaxf(md, a_d[i]);
    }
    shs[t] = ms; shd[t] = md; __syncthreads();
    for (int off = 128; off >= 4; off >>= 1){
        if (t < off){ shs[t] = fmaxf(shs[t], shs[t+off]); shd[t] = fmaxf(shd[t], shd[t+off]); }
        __syncthreads();
    }
    if (t < 4){ bmax_s[blockIdx.x*4+t] = shs[t]; bmax_d[blockIdx.x*4+t] = shd[t]; }
}
__global__ void k_headmax2(const float* __restrict__ bmax_s, const float* __restrict__ bmax_d,
                           float* __restrict__ mxs, int nb){
    int t = threadIdx.x;
    if (blockIdx.x != 0 || t >= 8) return;
    const float* src = (t < 4) ? bmax_s : bmax_d;
    int hh = t & 3;
    float m = -1e30f;
    for (int i = 0; i < nb; i++) m = fmaxf(m, src[i*4+hh]);
    mxs[t] = m;
}

__device__ __forceinline__ float leaky(float t){ return t > 0.f ? t : NEG*t; }

// ---------- gather: 8 nodes/wave, 8 lanes/node, 16B loads ----------
__global__ __launch_bounds__(256) void k_gather(const __half* __restrict__ ht16,
        const __half* __restrict__ G16,
        const float* __restrict__ a_s, const float* __restrict__ a_d,
        const float* __restrict__ mxs, const float* __restrict__ dinv,
        const int* __restrict__ row_ptr, const int* __restrict__ re_col,
        const int* __restrict__ col_ptr, const int* __restrict__ ce_row,
        __half* __restrict__ Aj16, __half* __restrict__ xg16, int N){
    int lane = threadIdx.x & 63;
    int grp  = lane >> 3;
    int sub  = lane & 7;
    int hh   = sub >> 1;
    int wid  = (blockIdx.x*blockDim.x + threadIdx.x) >> 6;
    int v    = wid*8 + grp;
    if (v >= N) return;
    const us8* htb = (const us8*)ht16;
    const us8* gb  = (const us8*)G16;
    float sh = leaky(mxs[hh] + mxs[4+hh]);
    int rs = row_ptr[v], re = row_ptr[v+1];
    float a0[8] = {0,0,0,0,0,0,0,0}, a1[8] = {0,0,0,0,0,0,0,0};
    float a2[8] = {0,0,0,0,0,0,0,0}, a3[8] = {0,0,0,0,0,0,0,0};
    int i = rs;
    for (; i + 3 < re; i += 4){
        us8 q0 = htb[(size_t)re_col[i]*8 + sub];
        us8 q1 = htb[(size_t)re_col[i+1]*8 + sub];
        us8 q2 = htb[(size_t)re_col[i+2]*8 + sub];
        us8 q3 = htb[(size_t)re_col[i+3]*8 + sub];
        #pragma unroll
        for (int j = 0; j < 8; j++){
            a0[j] += __half2float(__ushort_as_half(q0[j]));
            a1[j] += __half2float(__ushort_as_half(q1[j]));
            a2[j] += __half2float(__ushort_as_half(q2[j]));
            a3[j] += __half2float(__ushort_as_half(q3[j]));
        }
    }
    for (; i < re; i++){
        us8 q0 = htb[(size_t)re_col[i]*8 + sub];
        #pragma unroll
        for (int j = 0; j < 8; j++) a0[j] += __half2float(__ushort_as_half(q0[j]));
    }
    float dv = dinv[v];
    us8 pa;
    #pragma unroll
    for (int j = 0; j < 8; j++)
        pa[j] = __half_as_ushort(__float2half(dv*((a0[j]+a1[j]) + (a2[j]+a3[j]))));
    ((us8*)Aj16)[(size_t)v*8 + sub] = pa;
    float adv = a_d[v*4+hh];
    float eesl = __expf(leaky(a_s[v*4+hh] + adv) - sh);
    float s0 = eesl, s1 = 0.f, s2 = 0.f, s3 = 0.f;
    {
        us8 g0 = gb[(size_t)v*8 + sub];
        #pragma unroll
        for (int j = 0; j < 8; j++){
            a0[j] = eesl * __half2float(__ushort_as_half(g0[j]));
            a1[j] = 0.f; a2[j] = 0.f; a3[j] = 0.f;
        }
    }
    int cs = col_ptr[v], ce = col_ptr[v+1];
    i = cs;
    for (; i + 3 < ce; i += 4){
        int r0 = ce_row[i], r1 = ce_row[i+1], r2 = ce_row[i+2], r3 = ce_row[i+3];
        float e0 = __expf(leaky(a_s[r0*4+hh] + adv) - sh);
        float e1 = __expf(leaky(a_s[r1*4+hh] + adv) - sh);
        float e2 = __expf(leaky(a_s[r2*4+hh] + adv) - sh);
        float e3 = __expf(leaky(a_s[r3*4+hh] + adv) - sh);
        us8 q0 = gb[(size_t)r0*8 + sub];
        us8 q1 = gb[(size_t)r1*8 + sub];
        us8 q2 = gb[(size_t)r2*8 + sub];
        us8 q3 = gb[(size_t)r3*8 + sub];
        #pragma unroll
        for (int j = 0; j < 8; j++){
            a0[j] += e0 * __half2float(__ushort_as_half(q0[j]));
            a1[j] += e1 * __half2float(__ushort_as_half(q1[j]));
            a2[j] += e2 * __half2float(__ushort_as_half(q2[j]));
            a3[j] += e3 * __half2float(__ushort_as_half(q3[j]));
        }
        s0 += e0; s1 += e1; s2 += e2; s3 += e3;
    }
    for (; i < ce; i++){
        int r0 = ce_row[i];
        float e0 = __expf(leaky(a_s[r0*4+hh] + adv) - sh);
        us8 q0 = gb[(size_t)r0*8 + sub];
        #pragma unroll
        for (int j = 0; j < 8; j++) a0[j] += e0 * __half2float(__ushort_as_half(q0[j]));
        s0 += e0;
    }
    float inv = 1.f/((s0+s1)+(s2+s3));
    us8 px;
    #pragma unroll
    for (int j = 0; j < 8; j++)
        px[j] = __half_as_ushort(__float2half(((a0[j]+a1[j]) + (a2[j]+a3[j]))*inv));
    ((us8*)xg16)[(size_t)v*8 + sub] = px;
}

// ---------- fuse (MFMA): y = [Aj|xg] @ W, + bias + residual + LN + ReLU ----------
// one wave = 16-node tile; A[m=lane&15][k=quad*8+j]; D col=lane&15, row=quad*4+reg
__global__ __launch_bounds__(256) void k_fuse(float* __restrict__ h,
        const __half* __restrict__ Aj16, const __half* __restrict__ xg16,
        const float* __restrict__ dinv, __half* __restrict__ ht16,
        const _Float16* __restrict__ Bfrag, const float* __restrict__ b2c,
        const float* __restrict__ ln_g, const float* __restrict__ ln_b, int N){
    int lane = threadIdx.x & 63;
    int q = lane >> 4, c = lane & 15;
    half8 B[4][4];
    const half8* Bp = (const half8*)Bfrag;
    #pragma unroll
    for (int t = 0; t < 4; t++)
        #pragma unroll
        for (int kk = 0; kk < 4; kk++)
            B[t][kk] = Bp[(t*4+kk)*64 + lane];
    float bj[4], lg[4], lb[4];
    #pragma unroll
    for (int t = 0; t < 4; t++){
        int n = t*16 + c;
        bj[t] = b2c[n]; lg[t] = ln_g[n]; lb[t] = ln_b[n];
    }
    int tiles = (N + 15) >> 4;
    int wid = (blockIdx.x*blockDim.x + threadIdx.x) >> 6;
    int nw  = (gridDim.x*blockDim.x) >> 6;
    for (int tile = wid; tile < tiles; tile += nw){
        int nb = tile << 4;
        int anode = nb + c; if (anode >= N) anode = N - 1;
        const half8* ap = (const half8*)(Aj16 + (size_t)anode*64);
        const half8* xp = (const half8*)(xg16 + (size_t)anode*64);
        half8 A0 = ap[q];
        half8 A1 = ap[4 + q];
        half8 A2 = xp[q];
        half8 A3 = xp[4 + q];
        f32x4 acc[4];
        #pragma unroll
        for (int t = 0; t < 4; t++){
            f32x4 z = {0.f, 0.f, 0.f, 0.f};
            z = __builtin_amdgcn_mfma_f32_16x16x32_f16(A0, B[t][0], z, 0, 0, 0);
            z = __builtin_amdgcn_mfma_f32_16x16x32_f16(A1, B[t][1], z, 0, 0, 0);
            z = __builtin_amdgcn_mfma_f32_16x16x32_f16(A2, B[t][2], z, 0, 0, 0);
            z = __builtin_amdgcn_mfma_f32_16x16x32_f16(A3, B[t][3], z, 0, 0, 0);
            acc[t] = z;
        }
        // epilogue: lane holds y[node=nb+q*4+r][n=t*16+c] in acc[t][r]
        float y[4][4];     // [t][r]
        #pragma unroll
        for (int r = 0; r < 4; r++){
            int node = nb + q*4 + r;
            int nd = node < N ? node : N - 1;
            #pragma unroll
            for (int t = 0; t < 4; t++)
                y[t][r] = acc[t][r] + bj[t] + h[(size_t)nd*64 + t*16 + c];
        }
        #pragma unroll
        for (int r = 0; r < 4; r++){
            int node = nb + q*4 + r;
            float s = (y[0][r] + y[1][r]) + (y[2][r] + y[3][r]);
            #pragma unroll
            for (int o = 1; o < 16; o <<= 1) s += __shfl_xor(s, o);
            float mu = s * (1.f/64.f);
            float d0 = y[0][r]-mu, d1 = y[1][r]-mu, d2 = y[2][r]-mu, d3 = y[3][r]-mu;
            float var = (d0*d0 + d1*d1) + (d2*d2 + d3*d3);
            #pragma unroll
            for (int o = 1; o < 16; o <<= 1) var += __shfl_xor(var, o);
            var *= (1.f/64.f);
            float rstd = rsqrtf(var + LNEPS);
            if (node < N){
                float dvv = dinv[node];
                #pragma unroll
                for (int t = 0; t < 4; t++){
                    float out = (y[t][r]-mu)*rstd*lg[t] + lb[t];
                    out = out > 0.f ? out : 0.f;
                    h[(size_t)node*64 + t*16 + c] = out;
                    ht16[(size_t)node*64 + t*16 + c] = __float2half(dvv*out);
                }
            }
        }
    }
}

// ---------- readout ----------
__global__ __launch_bounds__(256) void k_readout(const float* __restrict__ h,
        const float* __restrict__ W1, const float* __restrict__ b1,
        const float* __restrict__ W2, const float* __restrict__ b2,
        float* __restrict__ out, int N){
    __shared__ float W1t[64*32];
    for (int idx = threadIdx.x; idx < 2048; idx += 256){
        int k = idx >> 5, j = idx & 31;
        W1t[idx] = W1[j*64+k];
    }
    __syncthreads();
    int lane = threadIdx.x & 63;
    float w2  = (lane < 32) ? W2[lane] : 0.f;
    float b1v = (lane < 32) ? b1[lane] : 0.f;
    float b2v = b2[0];
    int wid = (blockIdx.x*blockDim.x + threadIdx.x) >> 6;
    int nw  = (gridDim.x*blockDim.x) >> 6;
    for (int v = wid; v < N; v += nw){
        float hj = h[(size_t)v*64+lane];
        float acc = b1v;
        #pragma unroll
        for (int k = 0; k < 64; k++){
            float hk = __shfl(hj, k);
            if (lane < 32) acc += hk * W1t[k*32+lane];
        }
        float h1 = acc > 0.f ? acc : 0.f;
        float p = h1 * w2;
        #pragma unroll
        for (int o = 1; o < 32; o <<= 1) p += __shfl_xor(p, o);
        if (lane == 0){
            float z = p + b2v;
            out[v] = 1.f/(1.f + __expf(-z));
        }
    }
}

extern "C" void kernel_launch(void* const* d_in, const int* in_sizes, int n_in,
                              void* d_out, int out_size, void* d_ws, size_t ws_size,
                              hipStream_t stream){
    const ushort_t* xs = (const ushort_t*)d_in[0];
    const int*      ei = (const int*)d_in[1];

    int N = in_sizes[0] / 64;
    int E = in_sizes[1] / 2;
    const int* row = ei;
    const int* col = ei + E;
    int NBK = (N + BWD - 1) / BWD;

    size_t stageF = (size_t)2*E;
    size_t mirF   = (size_t)N*32;
    size_t aliasF = stageF > mirF ? stageF : mirF;

    float* f = (float*)d_ws;
    size_t o = 0;
    int*   flags = (int*)(f + o); o += 16;
    float* P     = f + o; o += P_TOTAL + 63;
    float* h     = f + o; o += (size_t)N*64;
    __half* ht16 = (__half*)(f + o); o += mirF;
    __half* G16  = (__half*)(f + o); o += mirF;
    __half* Aj16 = (__half*)(f + o); size_t aoff = o; o += aliasF;
    __half* xg16 = (__half*)(f + o); size_t xoff = o; o += aliasF;
    uint2* stage_r = (uint2*)(f + aoff);
    uint2* stage_c = (uint2*)(f + xoff);
    float* a_s   = f + o; o += (size_t)N*4;
    float* a_d   = f + o; o += (size_t)N*4;
    float* mxs   = f + o; o += 16;
    float* bmax_s= f + o; o += 1024;
    float* bmax_d= f + o; o += 1024;
    float* dinv  = f + o; o += ((size_t)N + 15) & ~15ull;
    int* bcnt    = (int*)(f + o); o += 512;
    int* bptr_r  = (int*)(f + o); o += 512;
    int* bptr_c  = (int*)(f + o); o += 512;
    int* bcur_r  = (int*)(f + o); o += 512;
    int* bcur_c  = (int*)(f + o); o += 512;
    int* ptr_r   = (int*)(f + o); o += ((size_t)N + 16) & ~15ull;
    int* ptr_c   = (int*)(f + o); o += ((size_t)N + 16) & ~15ull;
    int* re_col  = (int*)(f + o); o += (size_t)E;
    int* ce_row  = (int*)(f + o); o += (size_t)E;
    float* W1c   = f + o; o += 3*4096;
    float* b2c   = f + o; o += 3*64;
    _Float16* Bfrag = (_Float16*)(f + o); o += 3*4096;   // 3*8192 fp16

    const float* emb_W   = P + 0;
    const float* emb_b   = P + 4096;
    const float* e8_W    = P + 4160;
    const float* gat_W   = P + 16448;
    const float* att_src = P + 28736;
    const float* att_dst = P + 28928;
    const float* gat_b   = P + 29120;
    const float* fus_W   = P + 29312;
    const float* fus_b   = P + 53888;
    const float* ln_g    = P + 54080;
    const float* ln_b    = P + 54272;
    const float* r_W1    = P + 54464;
    const float* r_b1    = P + 56512;
    const float* r_W2    = P + 56544;
    const float* r_b2    = P + 56576;

    k_detect<<<1, 64, 0, stream>>>(d_in[0], d_in[2], d_in[4], d_in[5], d_in[6], d_in[7],
                                   d_in[9], d_in[13], d_in[15], d_in[11], flags);
    k_convert<<<(P_TOTAL+255)/256, 256, 0, stream>>>(
        d_in[2],d_in[3],d_in[4],d_in[5],d_in[6],d_in[7],d_in[8],d_in[9],
        d_in[10],d_in[11],d_in[12],d_in[13],d_in[14],d_in[15],d_in[16], flags, P);

    hipMemsetAsync(bcnt, 0, 512*sizeof(int), stream);
    kb_hist<<<256, 1024, 0, stream>>>(row, col, bcnt, NBK, E);
    kb_scan<<<2, 256, 0, stream>>>(bcnt, bptr_r, bptr_c, bcur_r, bcur_c, NBK, E);
    kb_bin<<<256, 1024, 0, stream>>>(row, col, bcur_r, stage_r, NBK, E);
    kb_bin<<<256, 1024, 0, stream>>>(col, row, bcur_c, stage_c, NBK, E);
    kb_place<<<NBK, 1024, 0, stream>>>(stage_r, bptr_r, ptr_r, re_col, dinv, 0, N, E);
    kb_place<<<NBK, 1024, 0, stream>>>(stage_c, bptr_c, ptr_c, ce_row, dinv, 1, N, E);

    k_prew<<<48, 256, 0, stream>>>(fus_W, e8_W, gat_b, fus_b, W1c, b2c);
    k_prewB<<<(3*8192+255)/256, 256, 0, stream>>>(W1c, fus_W, Bfrag);
    k_embed<<<1024, 256, 0, stream>>>(xs, flags, emb_W, emb_b, dinv, h, ht16, N);

    int ggrid = (N + 31) / 32;
    int tiles = (N + 15) / 16;
    int fgrid = (tiles + 7) / 8;
    for (int i = 0; i < 3; i++){
        k_gat_g<<<1024, 256, 0, stream>>>(h, gat_W + (size_t)i*4096,
                                          att_src + i*64, att_dst + i*64,
                                          G16, a_s, a_d, N);
        k_headmax1<<<256, 256, 0, stream>>>(a_s, a_d, bmax_s, bmax_d, N*4);
        k_headmax2<<<1, 64, 0, stream>>>(bmax_s, bmax_d, mxs, 256);
        k_gather<<<ggrid, 256, 0, stream>>>(ht16, G16, a_s, a_d, mxs, dinv,
                                            ptr_r, re_col, ptr_c, ce_row,
                                            Aj16, xg16, N);
        k_fuse<<<fgrid, 256, 0, stream>>>(h, Aj16, xg16, dinv, ht16,
                                          Bfrag + (size_t)i*8192, b2c + i*64,
                                          ln_g + i*64, ln_b + i*64, N);
    }
    k_readout<<<1024, 256, 0, stream>>>(h, r_W1, r_b1, r_W2, r_b2, (float*)d_out, N);
}

// Round 15
// 956.458 us; speedup vs baseline: 4.5802x; 1.1942x over previous
//
#include <hip/hip_runtime.h>
#include <hip/hip_bf16.h>
#include <hip/hip_fp16.h>

typedef __hip_bfloat16 bf16;
typedef unsigned short ushort_t;
typedef unsigned short us8 __attribute__((ext_vector_type(8)));
typedef _Float16 half8 __attribute__((ext_vector_type(8)));
typedef float f32x4 __attribute__((ext_vector_type(4)));

#define NEG 0.2f
#define LNEPS 1e-5f
#define BWD 512                 // CSR bucket width (nodes)

__device__ __forceinline__ int plaus(unsigned int lo){
    lo &= 0x7FFFu;
    if (lo == 0) return 1;
    unsigned int ex = (lo >> 7) & 0xFF;
    return (ex >= 100 && ex <= 140) ? 1 : 0;
}

__device__ __forceinline__ float decode_slot(const ushort_t* s, long long i, int fl){
    long long base = i << fl;
    unsigned int hi = s[base + fl];
    unsigned int lo = s[base];
    unsigned int bits = (hi << 16) | (lo * (unsigned int)fl);
    return __uint_as_float(bits);
}

// ---------- per-tensor dtype flags ----------
__global__ void k_detect(const void* t0, const void* t1, const void* t2, const void* t3,
                         const void* t4, const void* t5, const void* t6, const void* t7,
                         const void* t8, const void* lng, int* flags){
    int t = threadIdx.x;
    if (blockIdx.x != 0) return;
    if (t < 9){
        const void* ptrs[9] = {t0,t1,t2,t3,t4,t5,t6,t7,t8};
        const ushort_t* w = (const ushort_t*)ptrs[t];
        int all_bf = 1;
        for (int i = 0; i < 16; i++) all_bf &= plaus((unsigned int)w[i]);
        flags[t] = all_bf ? 0 : 1;
    } else if (t == 9){
        const ushort_t* w = (const ushort_t*)lng;
        flags[9] = (w[0] == 0x3F80u) ? 0 : 1;
    }
}

// ---------- stage params ----------
#define P_TOTAL 56577
__global__ void k_convert(const void* p0, const void* p1, const void* p2, const void* p3,
        const void* p4, const void* p5, const void* p6, const void* p7, const void* p8,
        const void* p9, const void* p10, const void* p11, const void* p12, const void* p13,
        const void* p14, const int* flags, float* P){
    int idx = blockIdx.x*blockDim.x + threadIdx.x;
    if (idx >= P_TOTAL) return;
    const int sizes[15] = {4096,64,12288,12288,192,192,192,24576,192,192,192,2048,32,32,1};
    const int fidx[15]  = {1,  -1,  2,    3,    4,  5,  -1, 6,    -1, 9,  -1, 7,   -1,8, -1};
    const void* ptrs[15] = {p0,p1,p2,p3,p4,p5,p6,p7,p8,p9,p10,p11,p12,p13,p14};
    int s = 0, base = 0;
    while (idx - base >= sizes[s]){ base += sizes[s]; s++; }
    int li = idx - base;
    int fi = fidx[s];
    int fl = (fi >= 0) ? flags[fi] : 0;
    P[idx] = decode_slot((const ushort_t*)ptrs[s], li, fl);
}

// ---------- bucketed CSR build ----------
__global__ __launch_bounds__(1024) void kb_hist(const int* __restrict__ row,
        const int* __restrict__ col, int* __restrict__ bcnt, int NBK, int E){
    __shared__ int lh[512];
    int t = threadIdx.x;
    for (int i = t; i < 2*NBK; i += 1024) lh[i] = 0;
    __syncthreads();
    for (long long e = (long long)blockIdx.x*1024 + t; e < E; e += (long long)gridDim.x*1024){
        atomicAdd(&lh[row[e] >> 9], 1);
        atomicAdd(&lh[NBK + (col[e] >> 9)], 1);
    }
    __syncthreads();
    for (int i = t; i < 2*NBK; i += 1024){
        int v = lh[i];
        if (v) atomicAdd(&bcnt[i], v);
    }
}

__global__ __launch_bounds__(256) void kb_scan(const int* __restrict__ bcnt,
        int* __restrict__ bptr_r, int* __restrict__ bptr_c,
        int* __restrict__ bcur_r, int* __restrict__ bcur_c, int NBK, int E){
    __shared__ int sh[256];
    int side = blockIdx.x;
    const int* c = bcnt + side*NBK;
    int* bp = side ? bptr_c : bptr_r;
    int* bc = side ? bcur_c : bcur_r;
    int t = threadIdx.x;
    int v = (t < NBK) ? c[t] : 0;
    sh[t] = v; __syncthreads();
    for (int off = 1; off < 256; off <<= 1){
        int add = (t >= off) ? sh[t-off] : 0;
        __syncthreads();
        sh[t] += add;
        __syncthreads();
    }
    if (t < NBK){ int e = sh[t] - v; bp[t] = e; bc[t] = e; }
    if (t == 0) bp[NBK] = E;
}

__global__ __launch_bounds__(1024) void kb_bin(const int* __restrict__ key,
        const int* __restrict__ pay, int* __restrict__ bcur,
        uint2* __restrict__ stage, int NBK, int E){
    __shared__ int lh[256], lbase[256];
    int t = threadIdx.x;
    for (long long tile = (long long)blockIdx.x*1024; tile < E; tile += (long long)gridDim.x*1024){
        for (int i = t; i < NBK; i += 1024) lh[i] = 0;
        __syncthreads();
        int e = (int)tile + t;
        int k = 0, p = 0, b = -1, rank = 0;
        if (e < E){
            k = key[e]; p = pay[e]; b = k >> 9;
            rank = atomicAdd(&lh[b], 1);
        }
        __syncthreads();
        for (int i = t; i < NBK; i += 1024){
            int c = lh[i];
            lbase[i] = c ? atomicAdd(&bcur[i], c) : 0;
        }
        __syncthreads();
        if (b >= 0) stage[lbase[b] + rank] = make_uint2((unsigned)k, (unsigned)p);
        __syncthreads();
    }
}

__global__ __launch_bounds__(1024) void kb_place(const uint2* __restrict__ stage,
        const int* __restrict__ bptr, int* __restrict__ ptr, int* __restrict__ outarr,
        float* __restrict__ dinv, int wantdinv, int N, int E){
    __shared__ int lcnt[BWD], lsc[BWD], lcur[BWD];
    int b = blockIdx.x;
    int s = bptr[b], e = bptr[b+1];
    int nbase = b << 9;
    int t = threadIdx.x;
    if (t < BWD) lcnt[t] = 0;
    __syncthreads();
    for (int i = s + t; i < e; i += 1024)
        atomicAdd(&lcnt[stage[i].x - nbase], 1);
    __syncthreads();
    if (t < BWD) lsc[t] = lcnt[t];
    __syncthreads();
    for (int off = 1; off < BWD; off <<= 1){
        int add = (t >= off && t < BWD) ? lsc[t-off] : 0;
        __syncthreads();
        if (t < BWD) lsc[t] += add;
        __syncthreads();
    }
    if (t < BWD){
        int node = nbase + t;
        int excl = lsc[t] - lcnt[t];
        lcur[t] = excl;
        if (node < N){
            ptr[node] = s + excl;
            if (wantdinv) dinv[node] = lcnt[t] > 0 ? rsqrtf((float)lcnt[t]) : 0.f;
        }
    }
    if (b == 0 && t == 0) ptr[N] = E;
    __syncthreads();
    for (int i = s + t; i < e; i += 1024){
        uint2 rec = stage[i];
        int pos = s + atomicAdd(&lcur[rec.x - nbase], 1);
        outarr[pos] = (int)rec.y;
    }
}

// ---------- precompute fused weights ----------
__global__ void k_prew(const float* __restrict__ fus_W, const float* __restrict__ e8_W,
                       const float* __restrict__ gat_b, const float* __restrict__ fus_b,
                       float* __restrict__ W1c, float* __restrict__ b2c){
    int t = blockIdx.x*blockDim.x + threadIdx.x;
    if (t < 3*4096){
        int i = t >> 12, jq = t & 4095, j = jq >> 6, q = jq & 63;
        const float* fw = fus_W + (size_t)i*64*128 + (size_t)j*128;
        const float* ew = e8_W + (size_t)i*4096;
        float acc = 0.f;
        for (int p = 0; p < 64; p++) acc += fw[p] * ew[p*64+q];
        W1c[t] = acc;
    }
    if (t < 3*64){
        int i = t >> 6, j = t & 63;
        const float* fw = fus_W + (size_t)i*64*128 + (size_t)j*128 + 64;
        float acc = fus_b[i*64+j];
        for (int p = 0; p < 64; p++) acc += gat_b[i*64+p] * fw[p];
        b2c[t] = acc;
    }
}

// ---------- pre-swizzle fusion weights into MFMA B-fragment order (fp16) ----------
// Bfrag[i][((t*4+kk)*64+lane)*8+j] = W[k=kk*32+(lane>>4)*8+j][n=t*16+(lane&15)]
__global__ void k_prewB(const float* __restrict__ W1c, const float* __restrict__ fus_W,
                        _Float16* __restrict__ Bfrag){
    int idx = blockIdx.x*blockDim.x + threadIdx.x;
    if (idx >= 3*8192) return;
    int i = idx / 8192; int rem = idx & 8191;
    int j = rem & 7, lane = (rem >> 3) & 63, kk = (rem >> 9) & 3, t = rem >> 11;
    int k = kk*32 + (lane >> 4)*8 + j;
    int n = t*16 + (lane & 15);
    float v = (k < 64) ? W1c[i*4096 + n*64 + k]
                       : fus_W[(size_t)i*8192 + n*128 + 64 + (k - 64)];
    Bfrag[idx] = (_Float16)v;
}

// ---------- pre-swizzle gat_W into B-frag order: 4 t-tiles x 2 kk-steps ----------
__global__ void k_prewBg(const float* __restrict__ gat_W, _Float16* __restrict__ Bg){
    int idx = blockIdx.x*blockDim.x + threadIdx.x;
    if (idx >= 3*4096) return;
    int i = idx / 4096; int rem = idx & 4095;
    int j = rem & 7, lane = (rem >> 3) & 63, kk = (rem >> 9) & 1, t = rem >> 10;
    int k = kk*32 + (lane >> 4)*8 + j;
    int n = t*16 + (lane & 15);
    Bg[idx] = (_Float16)gat_W[(size_t)i*4096 + k*64 + n];
}

// ---------- embedding: h fp32 + h16 + ht16 = dinv*h ----------
__global__ __launch_bounds__(256) void k_embed(const ushort_t* __restrict__ xs,
        const int* __restrict__ flags, const float* __restrict__ W,
        const float* __restrict__ b, const float* __restrict__ dinv,
        float* __restrict__ h, __half* __restrict__ h16, __half* __restrict__ ht16, int N){
    __shared__ float Wt[64*64];
    for (int idx = threadIdx.x; idx < 4096; idx += 256){
        int k = idx >> 6, j = idx & 63;
        Wt[idx] = W[j*64+k];
    }
    __syncthreads();
    int fl = flags[0];
    int lane = threadIdx.x & 63;
    int wid  = (blockIdx.x*blockDim.x + threadIdx.x) >> 6;
    int nw   = (gridDim.x*blockDim.x) >> 6;
    float bj = b[lane];
    for (int v = wid; v < N; v += nw){
        float xj = decode_slot(xs, (long long)v*64 + lane, fl);
        float acc = bj;
        #pragma unroll
        for (int k = 0; k < 64; k++) acc += __shfl(xj, k) * Wt[k*64+lane];
        h[(size_t)v*64 + lane] = acc;
        h16[(size_t)v*64 + lane] = __float2half(acc);
        ht16[(size_t)v*64 + lane] = __float2half(dinv[v]*acc);
    }
}

// ---------- per-layer (MFMA): G16 = h16 @ gat_W, head sums a_s/a_d ----------
// one wave = 16-node tile; A[m=lane&15][k=quad*8+j]; D col=lane&15, row=quad*4+reg
__global__ __launch_bounds__(256) void k_gat_g(const __half* __restrict__ h16,
        const _Float16* __restrict__ Bg, const float* __restrict__ att_src,
        const float* __restrict__ att_dst, __half* __restrict__ G16,
        float* __restrict__ a_s, float* __restrict__ a_d, int N){
    int lane = threadIdx.x & 63;
    int q = lane >> 4, c = lane & 15;
    half8 B[4][2];
    const half8* Bp = (const half8*)Bg;
    #pragma unroll
    for (int t = 0; t < 4; t++)
        #pragma unroll
        for (int kk = 0; kk < 2; kk++)
            B[t][kk] = Bp[(t*2+kk)*64 + lane];
    float asv[4], adv[4];
    #pragma unroll
    for (int t = 0; t < 4; t++){
        asv[t] = att_src[t*16 + c];
        adv[t] = att_dst[t*16 + c];
    }
    int tiles = (N + 15) >> 4;
    int wid = (blockIdx.x*blockDim.x + threadIdx.x) >> 6;
    int nw  = (gridDim.x*blockDim.x) >> 6;
    for (int tile = wid; tile < tiles; tile += nw){
        int nb = tile << 4;
        int anode = nb + c; if (anode >= N) anode = N - 1;
        const half8* ap = (const half8*)(h16 + (size_t)anode*64);
        half8 A0 = ap[q];
        half8 A1 = ap[4 + q];
        f32x4 acc[4];
        #pragma unroll
        for (int t = 0; t < 4; t++){
            f32x4 z = {0.f, 0.f, 0.f, 0.f};
            z = __builtin_amdgcn_mfma_f32_16x16x32_f16(A0, B[t][0], z, 0, 0, 0);
            z = __builtin_amdgcn_mfma_f32_16x16x32_f16(A1, B[t][1], z, 0, 0, 0);
            acc[t] = z;
        }
        #pragma unroll
        for (int r = 0; r < 4; r++){
            int node = nb + q*4 + r;
            float tsv[4], tdv[4];
            #pragma unroll
            for (int t = 0; t < 4; t++){
                float s1 = acc[t][r]*asv[t];
                float s2 = acc[t][r]*adv[t];
                #pragma unroll
                for (int o = 1; o < 16; o <<= 1){
                    s1 += __shfl_xor(s1, o);
                    s2 += __shfl_xor(s2, o);
                }
                tsv[t] = s1; tdv[t] = s2;
            }
            if (node < N){
                #pragma unroll
                for (int t = 0; t < 4; t++)
                    G16[(size_t)node*64 + t*16 + c] = __float2half(acc[t][r]);
                if (c == 0){
                    #pragma unroll
                    for (int t = 0; t < 4; t++){
                        a_s[node*4+t] = tsv[t];
                        a_d[node*4+t] = tdv[t];
                    }
                }
            }
        }
    }
}

// ---------- per-head global maxes ----------
__global__ __launch_bounds__(256) void k_headmax1(const float* __restrict__ a_s,
        const float* __restrict__ a_d, float* __restrict__ bmax_s,
        float* __restrict__ bmax_d, int n4){
    __shared__ float shs[256], shd[256];
    int t = threadIdx.x;
    int S = gridDim.x * 256;
    float ms = -1e30f, md = -1e30f;
    for (int i = blockIdx.x*256 + t; i < n4; i += S){
        ms = fmaxf(ms, a_s[i]); md = fmaxf(md, a_d[i]);
    }
    shs[t] = ms; shd[t] = md; __syncthreads();
    for (int off = 128; off >= 4; off >>= 1){
        if (t < off){ shs[t] = fmaxf(shs[t], shs[t+off]); shd[t] = fmaxf(shd[t], shd[t+off]); }
        __syncthreads();
    }
    if (t < 4){ bmax_s[blockIdx.x*4+t] = shs[t]; bmax_d[blockIdx.x*4+t] = shd[t]; }
}
__global__ void k_headmax2(const float* __restrict__ bmax_s, const float* __restrict__ bmax_d,
                           float* __restrict__ mxs, int nb){
    int t = threadIdx.x;
    if (blockIdx.x != 0 || t >= 8) return;
    const float* src = (t < 4) ? bmax_s : bmax_d;
    int hh = t & 3;
    float m = -1e30f;
    for (int i = 0; i < nb; i++) m = fmaxf(m, src[i*4+hh]);
    mxs[t] = m;
}

__device__ __forceinline__ float leaky(float t){ return t > 0.f ? t : NEG*t; }

// ---------- gather: 8 nodes/wave, 8 lanes/node, 16B loads ----------
__global__ __launch_bounds__(256) void k_gather(const __half* __restrict__ ht16,
        const __half* __restrict__ G16,
        const float* __restrict__ a_s, const float* __restrict__ a_d,
        const float* __restrict__ mxs, const float* __restrict__ dinv,
        const int* __restrict__ row_ptr, const int* __restrict__ re_col,
        const int* __restrict__ col_ptr, const int* __restrict__ ce_row,
        __half* __restrict__ Aj16, __half* __restrict__ xg16, int N){
    int lane = threadIdx.x & 63;
    int grp  = lane >> 3;
    int sub  = lane & 7;
    int hh   = sub >> 1;
    int wid  = (blockIdx.x*blockDim.x + threadIdx.x) >> 6;
    int v    = wid*8 + grp;
    if (v >= N) return;
    const us8* htb = (const us8*)ht16;
    const us8* gb  = (const us8*)G16;
    float sh = leaky(mxs[hh] + mxs[4+hh]);
    int rs = row_ptr[v], re = row_ptr[v+1];
    float a0[8] = {0,0,0,0,0,0,0,0}, a1[8] = {0,0,0,0,0,0,0,0};
    float a2[8] = {0,0,0,0,0,0,0,0}, a3[8] = {0,0,0,0,0,0,0,0};
    int i = rs;
    for (; i + 3 < re; i += 4){
        us8 q0 = htb[(size_t)re_col[i]*8 + sub];
        us8 q1 = htb[(size_t)re_col[i+1]*8 + sub];
        us8 q2 = htb[(size_t)re_col[i+2]*8 + sub];
        us8 q3 = htb[(size_t)re_col[i+3]*8 + sub];
        #pragma unroll
        for (int j = 0; j < 8; j++){
            a0[j] += __half2float(__ushort_as_half(q0[j]));
            a1[j] += __half2float(__ushort_as_half(q1[j]));
            a2[j] += __half2float(__ushort_as_half(q2[j]));
            a3[j] += __half2float(__ushort_as_half(q3[j]));
        }
    }
    for (; i < re; i++){
        us8 q0 = htb[(size_t)re_col[i]*8 + sub];
        #pragma unroll
        for (int j = 0; j < 8; j++) a0[j] += __half2float(__ushort_as_half(q0[j]));
    }
    float dv = dinv[v];
    us8 pa;
    #pragma unroll
    for (int j = 0; j < 8; j++)
        pa[j] = __half_as_ushort(__float2half(dv*((a0[j]+a1[j]) + (a2[j]+a3[j]))));
    ((us8*)Aj16)[(size_t)v*8 + sub] = pa;
    float adv = a_d[v*4+hh];
    float eesl = __expf(leaky(a_s[v*4+hh] + adv) - sh);
    float s0 = eesl, s1 = 0.f, s2 = 0.f, s3 = 0.f;
    {
        us8 g0 = gb[(size_t)v*8 + sub];
        #pragma unroll
        for (int j = 0; j < 8; j++){
            a0[j] = eesl * __half2float(__ushort_as_half(g0[j]));
            a1[j] = 0.f; a2[j] = 0.f; a3[j] = 0.f;
        }
    }
    int cs = col_ptr[v], ce = col_ptr[v+1];
    i = cs;
    for (; i + 3 < ce; i += 4){
        int r0 = ce_row[i], r1 = ce_row[i+1], r2 = ce_row[i+2], r3 = ce_row[i+3];
        float e0 = __expf(leaky(a_s[r0*4+hh] + adv) - sh);
        float e1 = __expf(leaky(a_s[r1*4+hh] + adv) - sh);
        float e2 = __expf(leaky(a_s[r2*4+hh] + adv) - sh);
        float e3 = __expf(leaky(a_s[r3*4+hh] + adv) - sh);
        us8 q0 = gb[(size_t)r0*8 + sub];
        us8 q1 = gb[(size_t)r1*8 + sub];
        us8 q2 = gb[(size_t)r2*8 + sub];
        us8 q3 = gb[(size_t)r3*8 + sub];
        #pragma unroll
        for (int j = 0; j < 8; j++){
            a0[j] += e0 * __half2float(__ushort_as_half(q0[j]));
            a1[j] += e1 * __half2float(__ushort_as_half(q1[j]));
            a2[j] += e2 * __half2float(__ushort_as_half(q2[j]));
            a3[j] += e3 * __half2float(__ushort_as_half(q3[j]));
        }
        s0 += e0; s1 += e1; s2 += e2; s3 += e3;
    }
    for (; i < ce; i++){
        int r0 = ce_row[i];
        float e0 = __expf(leaky(a_s[r0*4+hh] + adv) - sh);
        us8 q0 = gb[(size_t)r0*8 + sub];
        #pragma unroll
        for (int j = 0; j < 8; j++) a0[j] += e0 * __half2float(__ushort_as_half(q0[j]));
        s0 += e0;
    }
    float inv = 1.f/((s0+s1)+(s2+s3));
    us8 px;
    #pragma unroll
    for (int j = 0; j < 8; j++)
        px[j] = __half_as_ushort(__float2half(((a0[j]+a1[j]) + (a2[j]+a3[j]))*inv));
    ((us8*)xg16)[(size_t)v*8 + sub] = px;
}

// ---------- fuse (MFMA): y = [Aj|xg] @ W, + bias + residual + LN + ReLU ----------
__global__ __launch_bounds__(256) void k_fuse(float* __restrict__ h,
        const __half* __restrict__ Aj16, const __half* __restrict__ xg16,
        const float* __restrict__ dinv, __half* __restrict__ h16,
        __half* __restrict__ ht16,
        const _Float16* __restrict__ Bfrag, const float* __restrict__ b2c,
        const float* __restrict__ ln_g, const float* __restrict__ ln_b, int N){
    int lane = threadIdx.x & 63;
    int q = lane >> 4, c = lane & 15;
    half8 B[4][4];
    const half8* Bp = (const half8*)Bfrag;
    #pragma unroll
    for (int t = 0; t < 4; t++)
        #pragma unroll
        for (int kk = 0; kk < 4; kk++)
            B[t][kk] = Bp[(t*4+kk)*64 + lane];
    float bj[4], lg[4], lb[4];
    #pragma unroll
    for (int t = 0; t < 4; t++){
        int n = t*16 + c;
        bj[t] = b2c[n]; lg[t] = ln_g[n]; lb[t] = ln_b[n];
    }
    int tiles = (N + 15) >> 4;
    int wid = (blockIdx.x*blockDim.x + threadIdx.x) >> 6;
    int nw  = (gridDim.x*blockDim.x) >> 6;
    for (int tile = wid; tile < tiles; tile += nw){
        int nb = tile << 4;
        int anode = nb + c; if (anode >= N) anode = N - 1;
        const half8* ap = (const half8*)(Aj16 + (size_t)anode*64);
        const half8* xp = (const half8*)(xg16 + (size_t)anode*64);
        half8 A0 = ap[q];
        half8 A1 = ap[4 + q];
        half8 A2 = xp[q];
        half8 A3 = xp[4 + q];
        f32x4 acc[4];
        #pragma unroll
        for (int t = 0; t < 4; t++){
            f32x4 z = {0.f, 0.f, 0.f, 0.f};
            z = __builtin_amdgcn_mfma_f32_16x16x32_f16(A0, B[t][0], z, 0, 0, 0);
            z = __builtin_amdgcn_mfma_f32_16x16x32_f16(A1, B[t][1], z, 0, 0, 0);
            z = __builtin_amdgcn_mfma_f32_16x16x32_f16(A2, B[t][2], z, 0, 0, 0);
            z = __builtin_amdgcn_mfma_f32_16x16x32_f16(A3, B[t][3], z, 0, 0, 0);
            acc[t] = z;
        }
        float y[4][4];     // [t][r]
        #pragma unroll
        for (int r = 0; r < 4; r++){
            int node = nb + q*4 + r;
            int nd = node < N ? node : N - 1;
            #pragma unroll
            for (int t = 0; t < 4; t++)
                y[t][r] = acc[t][r] + bj[t] + h[(size_t)nd*64 + t*16 + c];
        }
        #pragma unroll
        for (int r = 0; r < 4; r++){
            int node = nb + q*4 + r;
            float s = (y[0][r] + y[1][r]) + (y[2][r] + y[3][r]);
            #pragma unroll
            for (int o = 1; o < 16; o <<= 1) s += __shfl_xor(s, o);
            float mu = s * (1.f/64.f);
            float d0 = y[0][r]-mu, d1 = y[1][r]-mu, d2 = y[2][r]-mu, d3 = y[3][r]-mu;
            float var = (d0*d0 + d1*d1) + (d2*d2 + d3*d3);
            #pragma unroll
            for (int o = 1; o < 16; o <<= 1) var += __shfl_xor(var, o);
            var *= (1.f/64.f);
            float rstd = rsqrtf(var + LNEPS);
            if (node < N){
                float dvv = dinv[node];
                #pragma unroll
                for (int t = 0; t < 4; t++){
                    float out = (y[t][r]-mu)*rstd*lg[t] + lb[t];
                    out = out > 0.f ? out : 0.f;
                    h[(size_t)node*64 + t*16 + c] = out;
                    h16[(size_t)node*64 + t*16 + c] = __float2half(out);
                    ht16[(size_t)node*64 + t*16 + c] = __float2half(dvv*out);
                }
            }
        }
    }
}

// ---------- readout ----------
__global__ __launch_bounds__(256) void k_readout(const float* __restrict__ h,
        const float* __restrict__ W1, const float* __restrict__ b1,
        const float* __restrict__ W2, const float* __restrict__ b2,
        float* __restrict__ out, int N){
    __shared__ float W1t[64*32];
    for (int idx = threadIdx.x; idx < 2048; idx += 256){
        int k = idx >> 5, j = idx & 31;
        W1t[idx] = W1[j*64+k];
    }
    __syncthreads();
    int lane = threadIdx.x & 63;
    float w2  = (lane < 32) ? W2[lane] : 0.f;
    float b1v = (lane < 32) ? b1[lane] : 0.f;
    float b2v = b2[0];
    int wid = (blockIdx.x*blockDim.x + threadIdx.x) >> 6;
    int nw  = (gridDim.x*blockDim.x) >> 6;
    for (int v = wid; v < N; v += nw){
        float hj = h[(size_t)v*64+lane];
        float acc = b1v;
        #pragma unroll
        for (int k = 0; k < 64; k++){
            float hk = __shfl(hj, k);
            if (lane < 32) acc += hk * W1t[k*32+lane];
        }
        float h1 = acc > 0.f ? acc : 0.f;
        float p = h1 * w2;
        #pragma unroll
        for (int o = 1; o < 32; o <<= 1) p += __shfl_xor(p, o);
        if (lane == 0){
            float z = p + b2v;
            out[v] = 1.f/(1.f + __expf(-z));
        }
    }
}

extern "C" void kernel_launch(void* const* d_in, const int* in_sizes, int n_in,
                              void* d_out, int out_size, void* d_ws, size_t ws_size,
                              hipStream_t stream){
    const ushort_t* xs = (const ushort_t*)d_in[0];
    const int*      ei = (const int*)d_in[1];

    int N = in_sizes[0] / 64;
    int E = in_sizes[1] / 2;
    const int* row = ei;
    const int* col = ei + E;
    int NBK = (N + BWD - 1) / BWD;

    size_t stageF = (size_t)2*E;
    size_t mirF   = (size_t)N*32;
    size_t aliasF = stageF > mirF ? stageF : mirF;

    float* f = (float*)d_ws;
    size_t o = 0;
    int*   flags = (int*)(f + o); o += 16;
    float* P     = f + o; o += P_TOTAL + 63;
    float* h     = f + o; o += (size_t)N*64;
    __half* h16  = (__half*)(f + o); o += mirF;
    __half* ht16 = (__half*)(f + o); o += mirF;
    __half* G16  = (__half*)(f + o); o += mirF;
    __half* Aj16 = (__half*)(f + o); size_t aoff = o; o += aliasF;
    __half* xg16 = (__half*)(f + o); size_t xoff = o; o += aliasF;
    uint2* stage_r = (uint2*)(f + aoff);
    uint2* stage_c = (uint2*)(f + xoff);
    float* a_s   = f + o; o += (size_t)N*4;
    float* a_d   = f + o; o += (size_t)N*4;
    float* mxs   = f + o; o += 16;
    float* bmax_s= f + o; o += 1024;
    float* bmax_d= f + o; o += 1024;
    float* dinv  = f + o; o += ((size_t)N + 15) & ~15ull;
    int* bcnt    = (int*)(f + o); o += 512;
    int* bptr_r  = (int*)(f + o); o += 512;
    int* bptr_c  = (int*)(f + o); o += 512;
    int* bcur_r  = (int*)(f + o); o += 512;
    int* bcur_c  = (int*)(f + o); o += 512;
    int* ptr_r   = (int*)(f + o); o += ((size_t)N + 16) & ~15ull;
    int* ptr_c   = (int*)(f + o); o += ((size_t)N + 16) & ~15ull;
    int* re_col  = (int*)(f + o); o += (size_t)E;
    int* ce_row  = (int*)(f + o); o += (size_t)E;
    float* W1c   = f + o; o += 3*4096;
    float* b2c   = f + o; o += 3*64;
    _Float16* Bfrag = (_Float16*)(f + o); o += 3*4096;   // 3*8192 fp16
    _Float16* Bg    = (_Float16*)(f + o); o += 3*2048;   // 3*4096 fp16

    const float* emb_W   = P + 0;
    const float* emb_b   = P + 4096;
    const float* e8_W    = P + 4160;
    const float* gat_W   = P + 16448;
    const float* att_src = P + 28736;
    const float* att_dst = P + 28928;
    const float* gat_b   = P + 29120;
    const float* fus_W   = P + 29312;
    const float* fus_b   = P + 53888;
    const float* ln_g    = P + 54080;
    const float* ln_b    = P + 54272;
    const float* r_W1    = P + 54464;
    const float* r_b1    = P + 56512;
    const float* r_W2    = P + 56544;
    const float* r_b2    = P + 56576;

    k_detect<<<1, 64, 0, stream>>>(d_in[0], d_in[2], d_in[4], d_in[5], d_in[6], d_in[7],
                                   d_in[9], d_in[13], d_in[15], d_in[11], flags);
    k_convert<<<(P_TOTAL+255)/256, 256, 0, stream>>>(
        d_in[2],d_in[3],d_in[4],d_in[5],d_in[6],d_in[7],d_in[8],d_in[9],
        d_in[10],d_in[11],d_in[12],d_in[13],d_in[14],d_in[15],d_in[16], flags, P);

    hipMemsetAsync(bcnt, 0, 512*sizeof(int), stream);
    kb_hist<<<256, 1024, 0, stream>>>(row, col, bcnt, NBK, E);
    kb_scan<<<2, 256, 0, stream>>>(bcnt, bptr_r, bptr_c, bcur_r, bcur_c, NBK, E);
    kb_bin<<<256, 1024, 0, stream>>>(row, col, bcur_r, stage_r, NBK, E);
    kb_bin<<<256, 1024, 0, stream>>>(col, row, bcur_c, stage_c, NBK, E);
    kb_place<<<NBK, 1024, 0, stream>>>(stage_r, bptr_r, ptr_r, re_col, dinv, 0, N, E);
    kb_place<<<NBK, 1024, 0, stream>>>(stage_c, bptr_c, ptr_c, ce_row, dinv, 1, N, E);

    k_prew<<<48, 256, 0, stream>>>(fus_W, e8_W, gat_b, fus_b, W1c, b2c);
    k_prewB<<<(3*8192+255)/256, 256, 0, stream>>>(W1c, fus_W, Bfrag);
    k_prewBg<<<(3*4096+255)/256, 256, 0, stream>>>(gat_W, Bg);
    k_embed<<<1024, 256, 0, stream>>>(xs, flags, emb_W, emb_b, dinv, h, h16, ht16, N);

    int ggrid = (N + 31) / 32;
    int tiles = (N + 15) / 16;
    int fgrid = (tiles + 7) / 8;
    for (int i = 0; i < 3; i++){
        k_gat_g<<<fgrid, 256, 0, stream>>>(h16, Bg + (size_t)i*4096,
                                           att_src + i*64, att_dst + i*64,
                                           G16, a_s, a_d, N);
        k_headmax1<<<256, 256, 0, stream>>>(a_s, a_d, bmax_s, bmax_d, N*4);
        k_headmax2<<<1, 64, 0, stream>>>(bmax_s, bmax_d, mxs, 256);
        k_gather<<<ggrid, 256, 0, stream>>>(ht16, G16, a_s, a_d, mxs, dinv,
                                            ptr_r, re_col, ptr_c, ce_row,
                                            Aj16, xg16, N);
        k_fuse<<<fgrid, 256, 0, stream>>>(h, Aj16, xg16, dinv, h16, ht16,
                                          Bfrag + (size_t)i*8192, b2c + i*64,
                                          ln_g + i*64, ln_b + i*64, N);
    }
    k_readout<<<1024, 256, 0, stream>>>(h, r_W1, r_b1, r_W2, r_b2, (float*)d_out, N);
}